// Round 1
// baseline (851.805 us; speedup 1.0000x reference)
//
#include <hip/hip_runtime.h>
#include <math.h>

// Problem constants
// B=64, ROWS=7, COLS=7, D=1280, H=256, S=5, NEG=16, GRU_ROWS=6
// N_seq = B*COLS = 448 GRU sequences; valid (s,r) pairs: r < 6-s -> 20 pairs
// num_preds = 20 * 64 * 7 = 8960

// ---------------------------------------------------------------------------
// Tiled GEMM: C[M,N] = A[M,K] * B[N,K]^T (+bias[N]) (optional clip to [-1,1])
// AMODE 0: A row m at A + m*K (row-major)
// AMODE 1: A row m maps into encodings: m = r*448 + n, n = b*7+c,
//          element offset = ((b*7 + r)*7 + c)*1280
// Tile 64x64, K-tile 32, 256 threads, 4x4 micro-tile.
// Requires M%64==0, N%64==0, K%32==0 (true for all uses here).
// ---------------------------------------------------------------------------
template<int AMODE, bool BIAS, bool CLIP>
__global__ __launch_bounds__(256) void gemm_abt(
    const float* __restrict__ A, const float* __restrict__ Bm,
    const float* __restrict__ bias, float* __restrict__ C,
    int M, int N, int K)
{
  __shared__ float As[32][68];  // k-major, stride 68 keeps 16B align + bank spread
  __shared__ float Bs[32][68];
  const int t  = threadIdx.x;
  const int tx = t & 15, ty = t >> 4;
  const int bx = blockIdx.x, by = blockIdx.y;

  float acc[4][4] = {};

  for (int k0 = 0; k0 < K; k0 += 32) {
#pragma unroll
    for (int i = 0; i < 2; ++i) {
      int f  = i * 256 + t;
      int rl = f >> 3;        // 0..63
      int kv = f & 7;         // 0..7 (float4 within 32-wide k tile)
      // A tile
      int m = by * 64 + rl;
      int aoff;
      if (AMODE == 0) {
        aoff = m * K;
      } else {
        int r = m / 448, n = m % 448;
        int b = n / 7,   c = n % 7;
        aoff = ((b * 7 + r) * 7 + c) * 1280;
      }
      float4 v = *(const float4*)&A[aoff + k0 + kv * 4];
      As[kv*4+0][rl] = v.x; As[kv*4+1][rl] = v.y;
      As[kv*4+2][rl] = v.z; As[kv*4+3][rl] = v.w;
      // B tile
      int cg = bx * 64 + rl;
      float4 w = *(const float4*)&Bm[cg * K + k0 + kv * 4];
      Bs[kv*4+0][rl] = w.x; Bs[kv*4+1][rl] = w.y;
      Bs[kv*4+2][rl] = w.z; Bs[kv*4+3][rl] = w.w;
    }
    __syncthreads();
#pragma unroll
    for (int kk = 0; kk < 32; ++kk) {
      float4 a = *(const float4*)&As[kk][ty * 4];
      float4 b = *(const float4*)&Bs[kk][tx * 4];
      float av[4] = {a.x, a.y, a.z, a.w};
      float bv[4] = {b.x, b.y, b.z, b.w};
#pragma unroll
      for (int i = 0; i < 4; ++i)
#pragma unroll
        for (int j = 0; j < 4; ++j)
          acc[i][j] = fmaf(av[i], bv[j], acc[i][j]);
    }
    __syncthreads();
  }

#pragma unroll
  for (int i = 0; i < 4; ++i) {
    int m = by * 64 + ty * 4 + i;
    float vals[4];
#pragma unroll
    for (int j = 0; j < 4; ++j) {
      float v = acc[i][j];
      if (BIAS) v += bias[bx * 64 + tx * 4 + j];
      if (CLIP) v = fminf(fmaxf(v, -1.f), 1.f);
      vals[j] = v;
    }
    float4 o; o.x = vals[0]; o.y = vals[1]; o.z = vals[2]; o.w = vals[3];
    *(float4*)&C[(size_t)m * N + bx * 64 + tx * 4] = o;
  }
}

// ---------------------------------------------------------------------------
// h init: broadcast hidden[256] to all 448 sequences
// ---------------------------------------------------------------------------
__global__ void h_init(const float* __restrict__ hidden, float* __restrict__ h)
{
  h[blockIdx.x * 256 + threadIdx.x] = hidden[threadIdx.x];
}

// ---------------------------------------------------------------------------
// GRU pointwise gate update (one step).
// gi_r: [448][768] (b_ih already added by GEMM), gh: [448][768] (no bias yet)
// h: [448][256] in/out;  ctx_r: [448][256] out
// ---------------------------------------------------------------------------
__global__ __launch_bounds__(256) void gru_point(
    const float* __restrict__ gi_r, const float* __restrict__ gh,
    const float* __restrict__ b_hh, float* __restrict__ h,
    float* __restrict__ ctx_r)
{
  const int n = blockIdx.x;    // 0..447
  const int t = threadIdx.x;   // 0..255
  const int gbase = n * 768;

  float ir = gi_r[gbase + t];
  float iz = gi_r[gbase + 256 + t];
  float in_ = gi_r[gbase + 512 + t];
  float hr = gh[gbase + t]        + b_hh[t];
  float hz = gh[gbase + 256 + t]  + b_hh[256 + t];
  float hn = gh[gbase + 512 + t]  + b_hh[512 + t];

  float r = 1.f / (1.f + expf(-(ir + hr)));
  float z = 1.f / (1.f + expf(-(iz + hz)));
  float ng = tanhf(in_ + r * hn);
  float hold = h[n * 256 + t];
  float hnew = (1.f - z) * ng + z * hold;
  h[n * 256 + t] = hnew;
  ctx_r[n * 256 + t] = hnew;
}

// ---------------------------------------------------------------------------
// dots[b,s,rr,q] = sum_d preds[r*448 + b*7 + c, d] * enc[b, q, d]
// One block per b (grid.x=64), for a given s. M = (6-s)*7 <= 42, N = 49, K = 1280.
// dots layout: [64][5][42][49]
// ---------------------------------------------------------------------------
__global__ __launch_bounds__(256) void dots_kernel(
    const float* __restrict__ preds, const float* __restrict__ enc,
    float* __restrict__ dots, int s)
{
  const int b = blockIdx.x;
  const int Mrs = (6 - s) * 7;
  __shared__ float At[64][48];  // k-major [kk][row], rows 0..41 valid
  __shared__ float Bt[64][64];  // k-major [kk][q],  q 0..48 valid

  const int t  = threadIdx.x;
  const int tx = t & 15, ty = t >> 4;

  float acc[3][4] = {};

  for (int k0 = 0; k0 < 1280; k0 += 64) {
    for (int f = t; f < Mrs * 16; f += 256) {
      int rr = f >> 4, kv = f & 15;
      int r = rr / 7, c = rr % 7;
      float4 v = *(const float4*)&preds[(size_t)(r * 448 + b * 7 + c) * 1280 + k0 + kv * 4];
      At[kv*4+0][rr] = v.x; At[kv*4+1][rr] = v.y;
      At[kv*4+2][rr] = v.z; At[kv*4+3][rr] = v.w;
    }
    for (int f = t; f < 49 * 16; f += 256) {
      int q = f >> 4, kv = f & 15;
      float4 v = *(const float4*)&enc[(size_t)(b * 49 + q) * 1280 + k0 + kv * 4];
      Bt[kv*4+0][q] = v.x; Bt[kv*4+1][q] = v.y;
      Bt[kv*4+2][q] = v.z; Bt[kv*4+3][q] = v.w;
    }
    __syncthreads();
#pragma unroll
    for (int kk = 0; kk < 64; ++kk) {
      float a0 = At[kk][ty], a1 = At[kk][ty + 16], a2 = At[kk][ty + 32];
      float b0 = Bt[kk][tx], b1 = Bt[kk][tx + 16];
      float b2 = Bt[kk][tx + 32], b3 = Bt[kk][tx + 48];
      acc[0][0] = fmaf(a0, b0, acc[0][0]); acc[0][1] = fmaf(a0, b1, acc[0][1]);
      acc[0][2] = fmaf(a0, b2, acc[0][2]); acc[0][3] = fmaf(a0, b3, acc[0][3]);
      acc[1][0] = fmaf(a1, b0, acc[1][0]); acc[1][1] = fmaf(a1, b1, acc[1][1]);
      acc[1][2] = fmaf(a1, b2, acc[1][2]); acc[1][3] = fmaf(a1, b3, acc[1][3]);
      acc[2][0] = fmaf(a2, b0, acc[2][0]); acc[2][1] = fmaf(a2, b1, acc[2][1]);
      acc[2][2] = fmaf(a2, b2, acc[2][2]); acc[2][3] = fmaf(a2, b3, acc[2][3]);
    }
    __syncthreads();
  }

#pragma unroll
  for (int i = 0; i < 3; ++i) {
    int row = ty + 16 * i;
    if (row < Mrs) {
#pragma unroll
      for (int j = 0; j < 4; ++j) {
        int q = tx + 16 * j;
        if (q < 49)
          dots[((size_t)(b * 5 + s) * 42 + row) * 49 + q] = acc[i][j];
      }
    }
  }
}

// ---------------------------------------------------------------------------
// Per-tuple log-softmax loss + accuracy, reduced into accbuf[2] via atomics.
// 8960 valid tuples: gid -> (b, p, c), p -> (s, r) with r < 6-s.
// ---------------------------------------------------------------------------
__global__ __launch_bounds__(256) void loss_kernel(
    const float* __restrict__ dots, const int* __restrict__ neg_rows,
    const int* __restrict__ neg_cols, float* __restrict__ accbuf)
{
  int gid = blockIdx.x * 256 + threadIdx.x;
  float lsum = 0.f, csum = 0.f;
  if (gid < 8960) {
    int b = gid / 140;
    int rem = gid % 140;
    int p = rem / 7, c = rem % 7;
    int s, r;
    if      (p < 6)  { s = 0; r = p; }
    else if (p < 11) { s = 1; r = p - 6; }
    else if (p < 15) { s = 2; r = p - 11; }
    else if (p < 18) { s = 3; r = p - 15; }
    else             { s = 4; r = p - 18; }

    const float* drow = &dots[((size_t)(b * 5 + s) * 42 + r * 7 + c) * 49];
    float d[17];
    d[0] = drow[r * 7 + c];  // positive: q = r*7 + c
    const int nbase = (((b * 5 + s) * 6 + r) * 7 + c) * 16;
#pragma unroll
    for (int j = 0; j < 16; ++j) {
      int q = neg_rows[nbase + j] * 7 + neg_cols[nbase + j];
      d[1 + j] = drow[q];
    }
    float m = d[0];
#pragma unroll
    for (int j = 1; j < 17; ++j) m = fmaxf(m, d[j]);
    float se = 0.f;
#pragma unroll
    for (int j = 0; j < 17; ++j) se += expf(d[j] - m);
    lsum = -(d[0] - m - logf(se));
    csum = (d[0] >= m) ? 1.f : 0.f;  // argmax==0 (first-index tie rule)
  }

#pragma unroll
  for (int off = 32; off > 0; off >>= 1) {
    lsum += __shfl_down(lsum, off);
    csum += __shfl_down(csum, off);
  }
  __shared__ float red[8];
  int wid = threadIdx.x >> 6;
  if ((threadIdx.x & 63) == 0) { red[wid * 2] = lsum; red[wid * 2 + 1] = csum; }
  __syncthreads();
  if (threadIdx.x == 0) {
    atomicAdd(&accbuf[0], red[0] + red[2] + red[4] + red[6]);
    atomicAdd(&accbuf[1], red[1] + red[3] + red[5] + red[7]);
  }
}

__global__ void finalize(const float* __restrict__ accbuf, float* __restrict__ out)
{
  out[0] = accbuf[0] / 8960.f;
  out[1] = accbuf[1] / 8960.f;
}

// ---------------------------------------------------------------------------
extern "C" void kernel_launch(void* const* d_in, const int* in_sizes, int n_in,
                              void* d_out, int out_size, void* d_ws, size_t ws_size,
                              hipStream_t stream)
{
  const float* enc    = (const float*)d_in[0];  // [64,7,7,1280]
  const float* hidden = (const float*)d_in[1];  // [1,1,256]
  const float* w_ih   = (const float*)d_in[2];  // [768,1280]
  const float* w_hh   = (const float*)d_in[3];  // [768,256]
  const float* b_ih   = (const float*)d_in[4];  // [768]
  const float* b_hh   = (const float*)d_in[5];  // [768]
  const float* wk_w   = (const float*)d_in[6];  // [5,1280,256]
  const float* wk_b   = (const float*)d_in[7];  // [5,1280]
  const int* neg_rows = (const int*)d_in[8];    // [64,5,6,7,16]
  const int* neg_cols = (const int*)d_in[9];
  float* out = (float*)d_out;                   // [2] (loss, acc)

  float* ws    = (float*)d_ws;
  float* accb  = ws;                       // 2 floats (pad to 64)
  float* gi    = ws + 64;                  // [6*448][768]   rows m=r*448+n
  float* gh    = gi + 6 * 448 * 768;       // [448][768]
  float* hbuf  = gh + 448 * 768;           // [448][256]
  float* ctx   = hbuf + 448 * 256;         // [6*448][256]   rows m=r*448+n
  float* preds = ctx + 6 * 448 * 256;      // [2688][1280]   rows m=r*448+n (valid r<6-s per s)
  float* dotsb = preds + 2688 * 1280;      // [64][5][42][49]

  hipMemsetAsync(accb, 0, 2 * sizeof(float), stream);
  h_init<<<448, 256, 0, stream>>>(hidden, hbuf);

  // gi = X @ w_ih^T + b_ih for all 6 rows at once (h-independent)
  gemm_abt<1, true, false><<<dim3(12, 42), 256, 0, stream>>>(
      enc, w_ih, b_ih, gi, 2688, 768, 1280);

  // 6 sequential GRU steps
  for (int r = 0; r < 6; ++r) {
    gemm_abt<0, false, false><<<dim3(12, 7), 256, 0, stream>>>(
        hbuf, w_hh, nullptr, gh, 448, 768, 256);
    gru_point<<<448, 256, 0, stream>>>(
        gi + (size_t)r * 448 * 768, gh, b_hh, hbuf, ctx + (size_t)r * 448 * 256);
  }

  // Per step s: preds = clip(ctx @ wk_w[s]^T + wk_b[s]); then dots vs 49 patches
  for (int s = 0; s < 5; ++s) {
    gemm_abt<0, true, true><<<dim3(20, (6 - s) * 7), 256, 0, stream>>>(
        ctx, wk_w + (size_t)s * 1280 * 256, wk_b + (size_t)s * 1280,
        preds, (6 - s) * 448, 1280, 256);
    dots_kernel<<<64, 256, 0, stream>>>(preds, enc, dotsb, s);
  }

  loss_kernel<<<35, 256, 0, stream>>>(dotsb, neg_rows, neg_cols, accb);
  finalize<<<1, 1, 0, stream>>>(accb, out);
}

// Round 2
// 253.173 us; speedup vs baseline: 3.3645x; 3.3645x over previous
//
#include <hip/hip_runtime.h>
#include <math.h>

// B=64, ROWS=7, COLS=7, D=1280, H=256, S=5, NEG=16, GRU_ROWS=6
// valid (s,r): r < 6-s -> 20 pairs; num_preds = 20*64*7 = 8960

typedef __bf16 bf16x8 __attribute__((ext_vector_type(8)));
typedef float  f32x4  __attribute__((ext_vector_type(4)));
typedef unsigned short u16;

__device__ inline u16 f2bf(float f) {           // RNE f32 -> bf16 bits
  unsigned int u = __float_as_uint(f);
  u += 0x7fff + ((u >> 16) & 1);
  return (u16)(u >> 16);
}

__device__ inline bf16x8 lds_frag(const char* sm, int off) {
  return __builtin_bit_cast(bf16x8, *(const uint4*)(sm + off));
}

// ---------------------------------------------------------------------------
// fp32 tiled GEMM (kept for GRU): C[M,N] = A[M,K]*B[N,K]^T (+bias)
// AMODE 1: A row m -> encodings row ((b*7+r)*7+c), m = r*448 + b*7 + c
// ---------------------------------------------------------------------------
template<int AMODE, bool BIAS>
__global__ __launch_bounds__(256) void gemm_abt(
    const float* __restrict__ A, const float* __restrict__ Bm,
    const float* __restrict__ bias, float* __restrict__ C,
    int M, int N, int K)
{
  __shared__ float As[32][68];
  __shared__ float Bs[32][68];
  const int t  = threadIdx.x;
  const int tx = t & 15, ty = t >> 4;
  const int bx = blockIdx.x, by = blockIdx.y;

  float acc[4][4] = {};

  for (int k0 = 0; k0 < K; k0 += 32) {
#pragma unroll
    for (int i = 0; i < 2; ++i) {
      int f  = i * 256 + t;
      int rl = f >> 3;
      int kv = f & 7;
      int m = by * 64 + rl;
      int aoff;
      if (AMODE == 0) {
        aoff = m * K;
      } else {
        int r = m / 448, n = m % 448;
        int b = n / 7,   c = n % 7;
        aoff = ((b * 7 + r) * 7 + c) * 1280;
      }
      float4 v = *(const float4*)&A[aoff + k0 + kv * 4];
      As[kv*4+0][rl] = v.x; As[kv*4+1][rl] = v.y;
      As[kv*4+2][rl] = v.z; As[kv*4+3][rl] = v.w;
      int cg = bx * 64 + rl;
      float4 w = *(const float4*)&Bm[cg * K + k0 + kv * 4];
      Bs[kv*4+0][rl] = w.x; Bs[kv*4+1][rl] = w.y;
      Bs[kv*4+2][rl] = w.z; Bs[kv*4+3][rl] = w.w;
    }
    __syncthreads();
#pragma unroll
    for (int kk = 0; kk < 32; ++kk) {
      float4 a = *(const float4*)&As[kk][ty * 4];
      float4 b = *(const float4*)&Bs[kk][tx * 4];
      float av[4] = {a.x, a.y, a.z, a.w};
      float bv[4] = {b.x, b.y, b.z, b.w};
#pragma unroll
      for (int i = 0; i < 4; ++i)
#pragma unroll
        for (int j = 0; j < 4; ++j)
          acc[i][j] = fmaf(av[i], bv[j], acc[i][j]);
    }
    __syncthreads();
  }

#pragma unroll
  for (int i = 0; i < 4; ++i) {
    int m = by * 64 + ty * 4 + i;
    float vals[4];
#pragma unroll
    for (int j = 0; j < 4; ++j) {
      float v = acc[i][j];
      if (BIAS) v += bias[bx * 64 + tx * 4 + j];
      vals[j] = v;
    }
    float4 o; o.x = vals[0]; o.y = vals[1]; o.z = vals[2]; o.w = vals[3];
    *(float4*)&C[(size_t)m * N + bx * 64 + tx * 4] = o;
  }
}

__global__ void h_init(const float* __restrict__ hidden, float* __restrict__ h)
{
  h[blockIdx.x * 256 + threadIdx.x] = hidden[threadIdx.x];
}

// GRU pointwise; ctx output stored as bf16 bits (feeds MFMA GEMM1)
__global__ __launch_bounds__(256) void gru_point(
    const float* __restrict__ gi_r, const float* __restrict__ gh,
    const float* __restrict__ b_hh, float* __restrict__ h,
    u16* __restrict__ ctxb)
{
  const int n = blockIdx.x;
  const int t = threadIdx.x;
  const int gbase = n * 768;

  float ir = gi_r[gbase + t];
  float iz = gi_r[gbase + 256 + t];
  float in_ = gi_r[gbase + 512 + t];
  float hr = gh[gbase + t]        + b_hh[t];
  float hz = gh[gbase + 256 + t]  + b_hh[256 + t];
  float hn = gh[gbase + 512 + t]  + b_hh[512 + t];

  float r = 1.f / (1.f + expf(-(ir + hr)));
  float z = 1.f / (1.f + expf(-(iz + hz)));
  float ng = tanhf(in_ + r * hn);
  float hold = h[n * 256 + t];
  float hnew = (1.f - z) * ng + z * hold;
  h[n * 256 + t] = hnew;
  ctxb[n * 256 + t] = f2bf(hnew);
}

// f32 -> bf16 bits, vectorized; n % 4 == 0
__global__ __launch_bounds__(256) void cvt_bf16(
    const float* __restrict__ src, u16* __restrict__ dst, int n)
{
  int i = (blockIdx.x * 256 + threadIdx.x) * 4;
  if (i < n) {
    float4 v = *(const float4*)&src[i];
    ushort4 o;
    o.x = f2bf(v.x); o.y = f2bf(v.y); o.z = f2bf(v.z); o.w = f2bf(v.w);
    *(ushort4*)&dst[i] = o;
  }
}

// ---------------------------------------------------------------------------
// Fused preds+dots, bf16 MFMA. Block (b, s). M=48 (42 valid), K1=256, N1=1280
// chunked by 64; GEMM2: dots[48][64] over K=1280, N=49 (padded 64).
// LDS tiles XOR-swizzled: byte_in_row ^= (row&7)<<4 (both write & read sides).
// ---------------------------------------------------------------------------
#define MFMA16(a, b, c) __builtin_amdgcn_mfma_f32_16x16x32_bf16(a, b, c, 0, 0, 0)

__global__ __launch_bounds__(256) void fused_pd(
    const u16* __restrict__ ctxb, const u16* __restrict__ wkwb,
    const float* __restrict__ wk_b, const u16* __restrict__ encb,
    float* __restrict__ dots)
{
  const int b = blockIdx.x;      // 0..63
  const int s = blockIdx.y;      // 0..4
  const int Ms = (6 - s) * 7;    // valid rows
  const int t = threadIdx.x;
  const int lane = t & 63, w = t >> 6;

  // LDS layout (bytes): ctxT[48][512] | Wt[64][512] | Et[64][128] | Pt[48][128]
  __shared__ uint4 smem4[71680 / 16];
  char* sm = (char*)smem4;
  const int CTX_OFF = 0, WT_OFF = 24576, ET_OFF = 57344, PT_OFF = 65536;

  // ---- stage ctx (once): 48 rows x 256 h bf16, 1536 16B-units
#pragma unroll
  for (int j = 0; j < 6; ++j) {
    int u = j * 256 + t;
    int row = u >> 5, slot = u & 31;
    int rr = row < Ms ? row : 0;
    int r = rr / 7, c = rr - r * 7;
    uint4 v = *(const uint4*)&ctxb[((size_t)(r * 448 + b * 7 + c)) * 256 + slot * 8];
    int off = row * 512 + ((slot * 16) ^ ((row & 7) << 4));
    *(uint4*)(sm + CTX_OFF + off) = v;
  }
  __syncthreads();

  // ---- hoist A1 fragments (ctx) into registers: 3 m-frags x 8 ksubs
  bf16x8 a1[3][8];
#pragma unroll
  for (int m = 0; m < 3; ++m)
#pragma unroll
    for (int ks = 0; ks < 8; ++ks) {
      int row = m * 16 + (lane & 15);
      int kb  = (ks * 64 + (lane >> 4) * 16) ^ ((row & 7) << 4);
      a1[m][ks] = lds_frag(sm, CTX_OFF + row * 512 + kb);
    }

  f32x4 acc2[3];
#pragma unroll
  for (int m = 0; m < 3; ++m) acc2[m] = (f32x4){0.f, 0.f, 0.f, 0.f};

  for (int ch = 0; ch < 20; ++ch) {
    const int d0 = ch * 64;
    if (ch) __syncthreads();   // Wt/Et free of prev GEMM2 readers

    // stage W chunk: 64 d-rows x 256 h bf16 (2048 units, 8/thread)
#pragma unroll
    for (int j = 0; j < 8; ++j) {
      int u = j * 256 + t;
      int row = u >> 5, slot = u & 31;
      uint4 v = *(const uint4*)&wkwb[((size_t)s * 1280 + d0 + row) * 256 + slot * 8];
      int off = row * 512 + ((slot * 16) ^ ((row & 7) << 4));
      *(uint4*)(sm + WT_OFF + off) = v;
    }
    // stage E chunk: 64 q-rows x 64 d bf16 (512 units, 2/thread)
#pragma unroll
    for (int j = 0; j < 2; ++j) {
      int u = j * 256 + t;
      int row = u >> 3, slot = u & 7;
      int q = row < 49 ? row : 0;
      uint4 v = *(const uint4*)&encb[((size_t)(b * 49 + q)) * 1280 + d0 + slot * 8];
      int off = row * 128 + ((slot * 16) ^ ((row & 7) << 4));
      *(uint4*)(sm + ET_OFF + off) = v;
    }
    __syncthreads();

    // GEMM1: P[48][64] = ctx . W^T ; wave w owns nd-frag w
    f32x4 acc1[3];
#pragma unroll
    for (int m = 0; m < 3; ++m) acc1[m] = (f32x4){0.f, 0.f, 0.f, 0.f};
#pragma unroll
    for (int ks = 0; ks < 8; ++ks) {
      int row = w * 16 + (lane & 15);
      int kb  = (ks * 64 + (lane >> 4) * 16) ^ ((row & 7) << 4);
      bf16x8 bfrag = lds_frag(sm, WT_OFF + row * 512 + kb);
      acc1[0] = MFMA16(a1[0][ks], bfrag, acc1[0]);
      acc1[1] = MFMA16(a1[1][ks], bfrag, acc1[1]);
      acc1[2] = MFMA16(a1[2][ks], bfrag, acc1[2]);
    }
    // epilogue: +bias, clip, ->bf16, scatter into Pt (C/D: col=lane&15, row=(lane>>4)*4+r)
    {
      int colL = w * 16 + (lane & 15);
      float bias = wk_b[s * 1280 + d0 + colL];
#pragma unroll
      for (int m = 0; m < 3; ++m)
#pragma unroll
        for (int r4 = 0; r4 < 4; ++r4) {
          float p = acc1[m][r4] + bias;
          p = fminf(fmaxf(p, -1.f), 1.f);
          int prow = m * 16 + (lane >> 4) * 4 + r4;
          int off  = prow * 128 + ((colL * 2) ^ ((prow & 7) << 4));
          *(u16*)(sm + PT_OFF + off) = f2bf(p);
        }
    }
    __syncthreads();

    // GEMM2: dots += P . E^T ; wave w owns q-frag w
#pragma unroll
    for (int ks = 0; ks < 2; ++ks) {
      int erow = w * 16 + (lane & 15);
      int ekb  = (ks * 64 + (lane >> 4) * 16) ^ ((erow & 7) << 4);
      bf16x8 efrag = lds_frag(sm, ET_OFF + erow * 128 + ekb);
#pragma unroll
      for (int m = 0; m < 3; ++m) {
        int prow = m * 16 + (lane & 15);
        int pkb  = (ks * 64 + (lane >> 4) * 16) ^ ((prow & 7) << 4);
        bf16x8 pfrag = lds_frag(sm, PT_OFF + prow * 128 + pkb);
        acc2[m] = MFMA16(pfrag, efrag, acc2[m]);
      }
    }
  }

  // store dots [64][5][42][49]
#pragma unroll
  for (int m = 0; m < 3; ++m)
#pragma unroll
    for (int r4 = 0; r4 < 4; ++r4) {
      int row = m * 16 + (lane >> 4) * 4 + r4;
      int q = w * 16 + (lane & 15);
      if (row < Ms && q < 49)
        dots[((size_t)(b * 5 + s) * 42 + row) * 49 + q] = acc2[m][r4];
    }
}

// ---------------------------------------------------------------------------
// Loss + accuracy over 8960 valid tuples -> accbuf[2]
// ---------------------------------------------------------------------------
__global__ __launch_bounds__(256) void loss_kernel(
    const float* __restrict__ dots, const int* __restrict__ neg_rows,
    const int* __restrict__ neg_cols, float* __restrict__ accbuf)
{
  int gid = blockIdx.x * 256 + threadIdx.x;
  float lsum = 0.f, csum = 0.f;
  if (gid < 8960) {
    int b = gid / 140;
    int rem = gid % 140;
    int p = rem / 7, c = rem % 7;
    int s, r;
    if      (p < 6)  { s = 0; r = p; }
    else if (p < 11) { s = 1; r = p - 6; }
    else if (p < 15) { s = 2; r = p - 11; }
    else if (p < 18) { s = 3; r = p - 15; }
    else             { s = 4; r = p - 18; }

    const float* drow = &dots[((size_t)(b * 5 + s) * 42 + r * 7 + c) * 49];
    float d[17];
    d[0] = drow[r * 7 + c];
    const int nbase = (((b * 5 + s) * 6 + r) * 7 + c) * 16;
#pragma unroll
    for (int j = 0; j < 16; ++j) {
      int q = neg_rows[nbase + j] * 7 + neg_cols[nbase + j];
      d[1 + j] = drow[q];
    }
    float m = d[0];
#pragma unroll
    for (int j = 1; j < 17; ++j) m = fmaxf(m, d[j]);
    float se = 0.f;
#pragma unroll
    for (int j = 0; j < 17; ++j) se += expf(d[j] - m);
    lsum = -(d[0] - m - logf(se));
    csum = (d[0] >= m) ? 1.f : 0.f;
  }

#pragma unroll
  for (int off = 32; off > 0; off >>= 1) {
    lsum += __shfl_down(lsum, off);
    csum += __shfl_down(csum, off);
  }
  __shared__ float red[8];
  int wid = threadIdx.x >> 6;
  if ((threadIdx.x & 63) == 0) { red[wid * 2] = lsum; red[wid * 2 + 1] = csum; }
  __syncthreads();
  if (threadIdx.x == 0) {
    atomicAdd(&accbuf[0], red[0] + red[2] + red[4] + red[6]);
    atomicAdd(&accbuf[1], red[1] + red[3] + red[5] + red[7]);
  }
}

__global__ void finalize(const float* __restrict__ accbuf, float* __restrict__ out)
{
  out[0] = accbuf[0] / 8960.f;
  out[1] = accbuf[1] / 8960.f;
}

// ---------------------------------------------------------------------------
extern "C" void kernel_launch(void* const* d_in, const int* in_sizes, int n_in,
                              void* d_out, int out_size, void* d_ws, size_t ws_size,
                              hipStream_t stream)
{
  const float* enc    = (const float*)d_in[0];
  const float* hidden = (const float*)d_in[1];
  const float* w_ih   = (const float*)d_in[2];
  const float* w_hh   = (const float*)d_in[3];
  const float* b_ih   = (const float*)d_in[4];
  const float* b_hh   = (const float*)d_in[5];
  const float* wk_w   = (const float*)d_in[6];
  const float* wk_b   = (const float*)d_in[7];
  const int* neg_rows = (const int*)d_in[8];
  const int* neg_cols = (const int*)d_in[9];
  float* out = (float*)d_out;

  float* ws    = (float*)d_ws;
  float* accb  = ws;                           // 64 f32
  float* gi    = ws + 64;                      // [6*448][768]
  float* gh    = gi + 6 * 448 * 768;           // [448][768]
  float* hbuf  = gh + 448 * 768;               // [448][256]
  u16*   ctxb  = (u16*)(hbuf + 448 * 256);     // [6*448][256] bf16
  u16*   encb  = ctxb + 6 * 448 * 256;         // [64*49][1280] bf16
  u16*   wkwb  = encb + 64 * 49 * 1280;        // [5][1280][256] bf16
  float* dotsb = (float*)(wkwb + 5 * 1280 * 256); // [64][5][42][49] f32

  hipMemsetAsync(accb, 0, 2 * sizeof(float), stream);
  h_init<<<448, 256, 0, stream>>>(hidden, hbuf);

  // bf16 copies of enc and wk_w (independent of GRU)
  cvt_bf16<<<(64 * 49 * 1280 / 4 + 255) / 256, 256, 0, stream>>>(enc, encb, 64 * 49 * 1280);
  cvt_bf16<<<(5 * 1280 * 256 / 4 + 255) / 256, 256, 0, stream>>>(wk_w, wkwb, 5 * 1280 * 256);

  // gi = X @ w_ih^T + b_ih for all 6 rows (h-independent)
  gemm_abt<1, true><<<dim3(12, 42), 256, 0, stream>>>(
      enc, w_ih, b_ih, gi, 2688, 768, 1280);

  // 6 sequential GRU steps
  for (int r = 0; r < 6; ++r) {
    gemm_abt<0, false><<<dim3(12, 7), 256, 0, stream>>>(
        hbuf, w_hh, nullptr, gh, 448, 768, 256);
    gru_point<<<448, 256, 0, stream>>>(
        gi + (size_t)r * 448 * 768, gh, b_hh, hbuf, ctxb + (size_t)r * 448 * 256);
  }

  // fused preds + dots (all s in one launch)
  fused_pd<<<dim3(64, 5), 256, 0, stream>>>(ctxb, wkwb, wk_b, encb, dotsb);

  loss_kernel<<<35, 256, 0, stream>>>(dotsb, neg_rows, neg_cols, accb);
  finalize<<<1, 1, 0, stream>>>(accb, out);
}

// Round 3
// 165.005 us; speedup vs baseline: 5.1623x; 1.5343x over previous
//
#include <hip/hip_runtime.h>
#include <math.h>

// B=64, ROWS=7, COLS=7, D=1280, H=256, S=5, NEG=16, GRU_ROWS=6
// valid (s,r): r < 6-s -> 20 pairs; num_preds = 20*64*7 = 8960

typedef __bf16 bf16x8 __attribute__((ext_vector_type(8)));
typedef float  f32x4  __attribute__((ext_vector_type(4)));
typedef unsigned short u16;

__device__ inline u16 f2bf(float f) {           // RNE f32 -> bf16 bits
  unsigned int u = __float_as_uint(f);
  u += 0x7fff + ((u >> 16) & 1);
  return (u16)(u >> 16);
}

__device__ inline bf16x8 lds_frag(const char* sm, int off) {
  return __builtin_bit_cast(bf16x8, *(const uint4*)(sm + off));
}

#define MFMA16(a, b, c) __builtin_amdgcn_mfma_f32_16x16x32_bf16(a, b, c, 0, 0, 0)

// ---------------------------------------------------------------------------
// f32 -> bf16 bits, vectorized; n % 4 == 0
// ---------------------------------------------------------------------------
__global__ __launch_bounds__(256) void cvt_bf16(
    const float* __restrict__ src, u16* __restrict__ dst, int n)
{
  int i = (blockIdx.x * 256 + threadIdx.x) * 4;
  if (i < n) {
    float4 v = *(const float4*)&src[i];
    ushort4 o;
    o.x = f2bf(v.x); o.y = f2bf(v.y); o.z = f2bf(v.z); o.w = f2bf(v.w);
    *(ushort4*)&dst[i] = o;
  }
}

// ---------------------------------------------------------------------------
// gi = enc @ w_ih^T + b_ih via bf16 MFMA.
// C[2688][768], K=1280. A row m -> encb row (b*49 + r*7 + c), m = r*448+b*7+c.
// Grid (6, 21), 256 thr = 4 waves (2x2), wave tile 64x64, BK=64.
// ---------------------------------------------------------------------------
__global__ __launch_bounds__(256) void gi_mfma(
    const u16* __restrict__ encb, const u16* __restrict__ wihb,
    const float* __restrict__ b_ih, float* __restrict__ gi)
{
  const int bx = blockIdx.x, by = blockIdx.y;
  const int t = threadIdx.x, lane = t & 63, w = t >> 6;
  const int wr = w >> 1, wc = w & 1;

  __shared__ char sm[32768];
  const int A_OFF = 0, B_OFF = 16384;   // each [128 rows][128 B] swizzled

  f32x4 acc[4][4];
#pragma unroll
  for (int i = 0; i < 4; ++i)
#pragma unroll
    for (int j = 0; j < 4; ++j) acc[i][j] = (f32x4){0.f, 0.f, 0.f, 0.f};

  for (int k0 = 0; k0 < 1280; k0 += 64) {
    if (k0) __syncthreads();
    // stage A: 128 rows x 64 bf16 (1024 uint4, 4/thread)
#pragma unroll
    for (int j = 0; j < 4; ++j) {
      int u = j * 256 + t;
      int row = u >> 3, slot = u & 7;
      int m = by * 128 + row;
      int r = m / 448, n = m - r * 448;
      int b = n / 7, c = n - b * 7;
      uint4 v = *(const uint4*)&encb[(size_t)(b * 49 + r * 7 + c) * 1280 + k0 + slot * 8];
      *(uint4*)(sm + A_OFF + row * 128 + ((slot * 16) ^ ((row & 7) << 4))) = v;
    }
    // stage B: 128 out-cols x 64 bf16
#pragma unroll
    for (int j = 0; j < 4; ++j) {
      int u = j * 256 + t;
      int row = u >> 3, slot = u & 7;
      uint4 v = *(const uint4*)&wihb[(size_t)(bx * 128 + row) * 1280 + k0 + slot * 8];
      *(uint4*)(sm + B_OFF + row * 128 + ((slot * 16) ^ ((row & 7) << 4))) = v;
    }
    __syncthreads();
#pragma unroll
    for (int ks = 0; ks < 2; ++ks) {
      bf16x8 a[4], b[4];
#pragma unroll
      for (int i = 0; i < 4; ++i) {
        int arow = wr * 64 + i * 16 + (lane & 15);
        int akb  = (ks * 64 + (lane >> 4) * 16) ^ ((arow & 7) << 4);
        a[i] = lds_frag(sm, A_OFF + arow * 128 + akb);
        int brow = wc * 64 + i * 16 + (lane & 15);
        int bkb  = (ks * 64 + (lane >> 4) * 16) ^ ((brow & 7) << 4);
        b[i] = lds_frag(sm, B_OFF + brow * 128 + bkb);
      }
#pragma unroll
      for (int i = 0; i < 4; ++i)
#pragma unroll
        for (int jn = 0; jn < 4; ++jn)
          acc[i][jn] = MFMA16(a[i], b[jn], acc[i][jn]);
    }
  }

#pragma unroll
  for (int i = 0; i < 4; ++i)
#pragma unroll
    for (int jn = 0; jn < 4; ++jn) {
      int gcol = bx * 128 + wc * 64 + jn * 16 + (lane & 15);
      float bias = b_ih[gcol];
#pragma unroll
      for (int r4 = 0; r4 < 4; ++r4) {
        int grow = by * 128 + wr * 64 + i * 16 + (lane >> 4) * 4 + r4;
        gi[(size_t)grow * 768 + gcol] = acc[i][jn][r4] + bias;
      }
    }
}

// ---------------------------------------------------------------------------
// Whole GRU in one kernel. 28 blocks x 512 thr (8 waves), 16 seqs per block.
// w_hh (bf16) lives entirely in registers: wave w owns output cols
// [w*96, w*96+96) -> 6 nfrags x 8 ksubs x 16B = 192 VGPR.
// Per step: gh = h_bf16 @ w_hh^T (MFMA, h from swizzled LDS), gh -> LDS,
// pointwise gate update in LDS, h_bf16 rewritten, ctx written to global.
// ---------------------------------------------------------------------------
__global__ __launch_bounds__(512, 2) void gru_fused(
    const u16* __restrict__ whhb, const float* __restrict__ b_hh,
    const float* __restrict__ hidden, const float* __restrict__ gi,
    u16* __restrict__ ctxb)
{
  const int n0 = blockIdx.x * 16;
  const int t = threadIdx.x, lane = t & 63, w = t >> 6;

  __shared__ char sm[77312];
  const int HBF = 0;          // [16][512B] swizzled bf16 h
  const int GH  = 8192;       // [16][776] f32 (pad 8 -> +32B/row bank shift)
  const int HF  = 57856;      // [16][256] f32
  const int BHH = 74240;      // [768] f32

  // resident weight fragments (one-time global loads)
  bf16x8 bfr[6][8];
#pragma unroll
  for (int nf = 0; nf < 6; ++nf) {
    int col = w * 96 + nf * 16 + (lane & 15);
#pragma unroll
    for (int ks = 0; ks < 8; ++ks)
      bfr[nf][ks] = *(const bf16x8*)&whhb[(size_t)col * 256 + ks * 32 + (lane >> 4) * 8];
  }

  // init b_hh + h
  for (int i = t; i < 768; i += 512) *(float*)(sm + BHH + i * 4) = b_hh[i];
  {
    int seq = t >> 5, c0 = (t & 31) * 8;
#pragma unroll
    for (int j = 0; j < 8; ++j) {
      int col = c0 + j;
      float hv = hidden[col];
      *(float*)(sm + HF + (seq * 256 + col) * 4) = hv;
      *(u16*)(sm + HBF + seq * 512 + ((col * 2) ^ ((seq & 7) << 4))) = f2bf(hv);
    }
  }

  for (int r = 0; r < 6; ++r) {
    __syncthreads();  // h (bf16) ready
    f32x4 acc[6];
#pragma unroll
    for (int nf = 0; nf < 6; ++nf) acc[nf] = (f32x4){0.f, 0.f, 0.f, 0.f};
#pragma unroll
    for (int ks = 0; ks < 8; ++ks) {
      int row = lane & 15;
      int kb = (ks * 64 + (lane >> 4) * 16) ^ ((row & 7) << 4);
      bf16x8 a = lds_frag(sm, HBF + row * 512 + kb);
#pragma unroll
      for (int nf = 0; nf < 6; ++nf) acc[nf] = MFMA16(a, bfr[nf][ks], acc[nf]);
    }
    // gh -> LDS (C/D: col=lane&15, row=(lane>>4)*4+r4)
#pragma unroll
    for (int nf = 0; nf < 6; ++nf) {
      int col = w * 96 + nf * 16 + (lane & 15);
#pragma unroll
      for (int r4 = 0; r4 < 4; ++r4) {
        int row = (lane >> 4) * 4 + r4;
        *(float*)(sm + GH + (row * 776 + col) * 4) = acc[nf][r4];
      }
    }
    __syncthreads();  // gh ready
    // pointwise: thread -> (seq = t>>5, cols c0..c0+7)
    {
      int seq = t >> 5, c0 = (t & 31) * 8;
      const float* gptr = &gi[((size_t)r * 448 + n0 + seq) * 768 + c0];
      u16 cv[8];
#pragma unroll
      for (int j = 0; j < 8; ++j) {
        int col = c0 + j;
        float ir  = gptr[j];
        float iz  = gptr[256 + j];
        float in_ = gptr[512 + j];
        float ghr = *(const float*)(sm + GH + (seq * 776 + col) * 4);
        float ghz = *(const float*)(sm + GH + (seq * 776 + 256 + col) * 4);
        float ghn = *(const float*)(sm + GH + (seq * 776 + 512 + col) * 4);
        float br = *(const float*)(sm + BHH + col * 4);
        float bz = *(const float*)(sm + BHH + (256 + col) * 4);
        float bn = *(const float*)(sm + BHH + (512 + col) * 4);
        float rg = 1.f / (1.f + expf(-(ir + ghr + br)));
        float zg = 1.f / (1.f + expf(-(iz + ghz + bz)));
        float ng = tanhf(in_ + rg * (ghn + bn));
        float hold = *(const float*)(sm + HF + (seq * 256 + col) * 4);
        float hnew = (1.f - zg) * ng + zg * hold;
        *(float*)(sm + HF + (seq * 256 + col) * 4) = hnew;
        *(u16*)(sm + HBF + seq * 512 + ((col * 2) ^ ((seq & 7) << 4))) = f2bf(hnew);
        cv[j] = f2bf(hnew);
      }
      *(uint4*)&ctxb[((size_t)r * 448 + n0 + seq) * 256 + c0] = *(uint4*)cv;
    }
  }
}

// ---------------------------------------------------------------------------
// Fused preds+dots, bf16 MFMA. Block (b, s). (unchanged from round 2)
// ---------------------------------------------------------------------------
__global__ __launch_bounds__(256) void fused_pd(
    const u16* __restrict__ ctxb, const u16* __restrict__ wkwb,
    const float* __restrict__ wk_b, const u16* __restrict__ encb,
    float* __restrict__ dots)
{
  const int b = blockIdx.x;      // 0..63
  const int s = blockIdx.y;      // 0..4
  const int Ms = (6 - s) * 7;    // valid rows
  const int t = threadIdx.x;
  const int lane = t & 63, w = t >> 6;

  __shared__ uint4 smem4[71680 / 16];
  char* sm = (char*)smem4;
  const int CTX_OFF = 0, WT_OFF = 24576, ET_OFF = 57344, PT_OFF = 65536;

#pragma unroll
  for (int j = 0; j < 6; ++j) {
    int u = j * 256 + t;
    int row = u >> 5, slot = u & 31;
    int rr = row < Ms ? row : 0;
    int r = rr / 7, c = rr - r * 7;
    uint4 v = *(const uint4*)&ctxb[((size_t)(r * 448 + b * 7 + c)) * 256 + slot * 8];
    int off = row * 512 + ((slot * 16) ^ ((row & 7) << 4));
    *(uint4*)(sm + CTX_OFF + off) = v;
  }
  __syncthreads();

  bf16x8 a1[3][8];
#pragma unroll
  for (int m = 0; m < 3; ++m)
#pragma unroll
    for (int ks = 0; ks < 8; ++ks) {
      int row = m * 16 + (lane & 15);
      int kb  = (ks * 64 + (lane >> 4) * 16) ^ ((row & 7) << 4);
      a1[m][ks] = lds_frag(sm, CTX_OFF + row * 512 + kb);
    }

  f32x4 acc2[3];
#pragma unroll
  for (int m = 0; m < 3; ++m) acc2[m] = (f32x4){0.f, 0.f, 0.f, 0.f};

  for (int ch = 0; ch < 20; ++ch) {
    const int d0 = ch * 64;
    if (ch) __syncthreads();

#pragma unroll
    for (int j = 0; j < 8; ++j) {
      int u = j * 256 + t;
      int row = u >> 5, slot = u & 31;
      uint4 v = *(const uint4*)&wkwb[((size_t)s * 1280 + d0 + row) * 256 + slot * 8];
      int off = row * 512 + ((slot * 16) ^ ((row & 7) << 4));
      *(uint4*)(sm + WT_OFF + off) = v;
    }
#pragma unroll
    for (int j = 0; j < 2; ++j) {
      int u = j * 256 + t;
      int row = u >> 3, slot = u & 7;
      int q = row < 49 ? row : 0;
      uint4 v = *(const uint4*)&encb[((size_t)(b * 49 + q)) * 1280 + d0 + slot * 8];
      int off = row * 128 + ((slot * 16) ^ ((row & 7) << 4));
      *(uint4*)(sm + ET_OFF + off) = v;
    }
    __syncthreads();

    f32x4 acc1[3];
#pragma unroll
    for (int m = 0; m < 3; ++m) acc1[m] = (f32x4){0.f, 0.f, 0.f, 0.f};
#pragma unroll
    for (int ks = 0; ks < 8; ++ks) {
      int row = w * 16 + (lane & 15);
      int kb  = (ks * 64 + (lane >> 4) * 16) ^ ((row & 7) << 4);
      bf16x8 bfrag = lds_frag(sm, WT_OFF + row * 512 + kb);
      acc1[0] = MFMA16(a1[0][ks], bfrag, acc1[0]);
      acc1[1] = MFMA16(a1[1][ks], bfrag, acc1[1]);
      acc1[2] = MFMA16(a1[2][ks], bfrag, acc1[2]);
    }
    {
      int colL = w * 16 + (lane & 15);
      float bias = wk_b[s * 1280 + d0 + colL];
#pragma unroll
      for (int m = 0; m < 3; ++m)
#pragma unroll
        for (int r4 = 0; r4 < 4; ++r4) {
          float p = acc1[m][r4] + bias;
          p = fminf(fmaxf(p, -1.f), 1.f);
          int prow = m * 16 + (lane >> 4) * 4 + r4;
          int off  = prow * 128 + ((colL * 2) ^ ((prow & 7) << 4));
          *(u16*)(sm + PT_OFF + off) = f2bf(p);
        }
    }
    __syncthreads();

#pragma unroll
    for (int ks = 0; ks < 2; ++ks) {
      int erow = w * 16 + (lane & 15);
      int ekb  = (ks * 64 + (lane >> 4) * 16) ^ ((erow & 7) << 4);
      bf16x8 efrag = lds_frag(sm, ET_OFF + erow * 128 + ekb);
#pragma unroll
      for (int m = 0; m < 3; ++m) {
        int prow = m * 16 + (lane & 15);
        int pkb  = (ks * 64 + (lane >> 4) * 16) ^ ((prow & 7) << 4);
        bf16x8 pfrag = lds_frag(sm, PT_OFF + prow * 128 + pkb);
        acc2[m] = MFMA16(pfrag, efrag, acc2[m]);
      }
    }
  }

#pragma unroll
  for (int m = 0; m < 3; ++m)
#pragma unroll
    for (int r4 = 0; r4 < 4; ++r4) {
      int row = m * 16 + (lane >> 4) * 4 + r4;
      int q = w * 16 + (lane & 15);
      if (row < Ms && q < 49)
        dots[((size_t)(b * 5 + s) * 42 + row) * 49 + q] = acc2[m][r4];
    }
}

// ---------------------------------------------------------------------------
// Loss + accuracy over 8960 valid tuples -> accbuf[2]
// ---------------------------------------------------------------------------
__global__ __launch_bounds__(256) void loss_kernel(
    const float* __restrict__ dots, const int* __restrict__ neg_rows,
    const int* __restrict__ neg_cols, float* __restrict__ accbuf)
{
  int gid = blockIdx.x * 256 + threadIdx.x;
  float lsum = 0.f, csum = 0.f;
  if (gid < 8960) {
    int b = gid / 140;
    int rem = gid % 140;
    int p = rem / 7, c = rem % 7;
    int s, r;
    if      (p < 6)  { s = 0; r = p; }
    else if (p < 11) { s = 1; r = p - 6; }
    else if (p < 15) { s = 2; r = p - 11; }
    else if (p < 18) { s = 3; r = p - 15; }
    else             { s = 4; r = p - 18; }

    const float* drow = &dots[((size_t)(b * 5 + s) * 42 + r * 7 + c) * 49];
    float d[17];
    d[0] = drow[r * 7 + c];
    const int nbase = (((b * 5 + s) * 6 + r) * 7 + c) * 16;
#pragma unroll
    for (int j = 0; j < 16; ++j) {
      int q = neg_rows[nbase + j] * 7 + neg_cols[nbase + j];
      d[1 + j] = drow[q];
    }
    float m = d[0];
#pragma unroll
    for (int j = 1; j < 17; ++j) m = fmaxf(m, d[j]);
    float se = 0.f;
#pragma unroll
    for (int j = 0; j < 17; ++j) se += expf(d[j] - m);
    lsum = -(d[0] - m - logf(se));
    csum = (d[0] >= m) ? 1.f : 0.f;
  }

#pragma unroll
  for (int off = 32; off > 0; off >>= 1) {
    lsum += __shfl_down(lsum, off);
    csum += __shfl_down(csum, off);
  }
  __shared__ float red[8];
  int wid = threadIdx.x >> 6;
  if ((threadIdx.x & 63) == 0) { red[wid * 2] = lsum; red[wid * 2 + 1] = csum; }
  __syncthreads();
  if (threadIdx.x == 0) {
    atomicAdd(&accbuf[0], red[0] + red[2] + red[4] + red[6]);
    atomicAdd(&accbuf[1], red[1] + red[3] + red[5] + red[7]);
  }
}

__global__ void finalize(const float* __restrict__ accbuf, float* __restrict__ out)
{
  out[0] = accbuf[0] / 8960.f;
  out[1] = accbuf[1] / 8960.f;
}

// ---------------------------------------------------------------------------
extern "C" void kernel_launch(void* const* d_in, const int* in_sizes, int n_in,
                              void* d_out, int out_size, void* d_ws, size_t ws_size,
                              hipStream_t stream)
{
  const float* enc    = (const float*)d_in[0];
  const float* hidden = (const float*)d_in[1];
  const float* w_ih   = (const float*)d_in[2];
  const float* w_hh   = (const float*)d_in[3];
  const float* b_ih   = (const float*)d_in[4];
  const float* b_hh   = (const float*)d_in[5];
  const float* wk_w   = (const float*)d_in[6];
  const float* wk_b   = (const float*)d_in[7];
  const int* neg_rows = (const int*)d_in[8];
  const int* neg_cols = (const int*)d_in[9];
  float* out = (float*)d_out;

  float* ws    = (float*)d_ws;
  float* accb  = ws;                               // 64 f32
  float* gi    = ws + 64;                          // [6*448][768] f32
  u16*   ctxb  = (u16*)(gi + 6 * 448 * 768);       // [6*448][256] bf16
  u16*   encb  = ctxb + 6 * 448 * 256;             // [64*49][1280] bf16
  u16*   wkwb  = encb + 64 * 49 * 1280;            // [5][1280][256] bf16
  u16*   wihb  = wkwb + 5 * 1280 * 256;            // [768][1280] bf16
  u16*   whhb  = wihb + 768 * 1280;                // [768][256] bf16
  float* dotsb = (float*)(whhb + 768 * 256 + 768); // [64][5][42][49] f32 (aligned)

  hipMemsetAsync(accb, 0, 2 * sizeof(float), stream);

  cvt_bf16<<<(64 * 49 * 1280 / 4 + 255) / 256, 256, 0, stream>>>(enc, encb, 64 * 49 * 1280);
  cvt_bf16<<<(5 * 1280 * 256 / 4 + 255) / 256, 256, 0, stream>>>(wk_w, wkwb, 5 * 1280 * 256);
  cvt_bf16<<<(768 * 1280 / 4 + 255) / 256, 256, 0, stream>>>(w_ih, wihb, 768 * 1280);
  cvt_bf16<<<(768 * 256 / 4 + 255) / 256, 256, 0, stream>>>(w_hh, whhb, 768 * 256);

  gi_mfma<<<dim3(6, 21), 256, 0, stream>>>(encb, wihb, b_ih, gi);

  gru_fused<<<28, 512, 0, stream>>>(whhb, b_hh, hidden, gi, ctxb);

  fused_pd<<<dim3(64, 5), 256, 0, stream>>>(ctxb, wkwb, wk_b, encb, dotsb);

  loss_kernel<<<35, 256, 0, stream>>>(dotsb, neg_rows, neg_cols, accb);
  finalize<<<1, 1, 0, stream>>>(accb, out);
}

// Round 4
// 156.218 us; speedup vs baseline: 5.4527x; 1.0563x over previous
//
#include <hip/hip_runtime.h>
#include <math.h>

// B=64, ROWS=7, COLS=7, D=1280, H=256, S=5, NEG=16, GRU_ROWS=6
// valid (s,r): r < 6-s -> 20 pairs; num_preds = 20*64*7 = 8960

typedef __bf16 bf16x8 __attribute__((ext_vector_type(8)));
typedef float  f32x4  __attribute__((ext_vector_type(4)));
typedef unsigned short u16;

__device__ inline u16 f2bf(float f) {           // RNE f32 -> bf16 bits
  unsigned int u = __float_as_uint(f);
  u += 0x7fff + ((u >> 16) & 1);
  return (u16)(u >> 16);
}

__device__ inline bf16x8 lds_frag(const char* sm, int off) {
  return __builtin_bit_cast(bf16x8, *(const uint4*)(sm + off));
}

#define MFMA16(a, b, c) __builtin_amdgcn_mfma_f32_16x16x32_bf16(a, b, c, 0, 0, 0)

// ---------------------------------------------------------------------------
// f32 -> bf16 bits, vectorized; n % 4 == 0
// ---------------------------------------------------------------------------
__global__ __launch_bounds__(256) void cvt_bf16(
    const float* __restrict__ src, u16* __restrict__ dst, int n)
{
  int i = (blockIdx.x * 256 + threadIdx.x) * 4;
  if (i < n) {
    float4 v = *(const float4*)&src[i];
    ushort4 o;
    o.x = f2bf(v.x); o.y = f2bf(v.y); o.z = f2bf(v.z); o.w = f2bf(v.w);
    *(ushort4*)&dst[i] = o;
  }
}

// ---------------------------------------------------------------------------
// Pack w_hh [768][256] f32 into per-lane MFMA B-fragment order (bf16):
// pk[((cb*8 + ks)*64 + lane)*8 + j] = bf16(w_hh[(cb*16 + (lane&15))*256
//                                              + ks*32 + (lane>>4)*8 + j])
// A wave's fragment load is then one contiguous 1 KB global_load_dwordx4.
// ---------------------------------------------------------------------------
__global__ __launch_bounds__(256) void pack_whh(
    const float* __restrict__ w_hh, u16* __restrict__ pk)
{
  int tid = blockIdx.x * 256 + threadIdx.x;  // 0..24575
  int lane = tid & 63;
  int rest = tid >> 6;                       // cb*8 + ks
  int cb = rest >> 3, ks = rest & 7;
  int col = cb * 16 + (lane & 15);
  int k = ks * 32 + (lane >> 4) * 8;
  const float* src = &w_hh[(size_t)col * 256 + k];
  float4 v0 = *(const float4*)src;
  float4 v1 = *(const float4*)(src + 4);
  u16 o[8] = {f2bf(v0.x), f2bf(v0.y), f2bf(v0.z), f2bf(v0.w),
              f2bf(v1.x), f2bf(v1.y), f2bf(v1.z), f2bf(v1.w)};
  *(uint4*)&pk[(size_t)tid * 8] = *(uint4*)o;
}

// ---------------------------------------------------------------------------
// gi = enc @ w_ih^T + b_ih via bf16 MFMA.
// C[2688][768], K=1280. A row m -> encb row (b*49 + r*7 + c), m = r*448+b*7+c.
// Grid (6, 21), 256 thr = 4 waves (2x2), wave tile 64x64, BK=64.
// ---------------------------------------------------------------------------
__global__ __launch_bounds__(256) void gi_mfma(
    const u16* __restrict__ encb, const u16* __restrict__ wihb,
    const float* __restrict__ b_ih, float* __restrict__ gi)
{
  const int bx = blockIdx.x, by = blockIdx.y;
  const int t = threadIdx.x, lane = t & 63, w = t >> 6;
  const int wr = w >> 1, wc = w & 1;

  __shared__ char sm[32768];
  const int A_OFF = 0, B_OFF = 16384;   // each [128 rows][128 B] swizzled

  f32x4 acc[4][4];
#pragma unroll
  for (int i = 0; i < 4; ++i)
#pragma unroll
    for (int j = 0; j < 4; ++j) acc[i][j] = (f32x4){0.f, 0.f, 0.f, 0.f};

  for (int k0 = 0; k0 < 1280; k0 += 64) {
    if (k0) __syncthreads();
#pragma unroll
    for (int j = 0; j < 4; ++j) {
      int u = j * 256 + t;
      int row = u >> 3, slot = u & 7;
      int m = by * 128 + row;
      int r = m / 448, n = m - r * 448;
      int b = n / 7, c = n - b * 7;
      uint4 v = *(const uint4*)&encb[(size_t)(b * 49 + r * 7 + c) * 1280 + k0 + slot * 8];
      *(uint4*)(sm + A_OFF + row * 128 + ((slot * 16) ^ ((row & 7) << 4))) = v;
    }
#pragma unroll
    for (int j = 0; j < 4; ++j) {
      int u = j * 256 + t;
      int row = u >> 3, slot = u & 7;
      uint4 v = *(const uint4*)&wihb[(size_t)(bx * 128 + row) * 1280 + k0 + slot * 8];
      *(uint4*)(sm + B_OFF + row * 128 + ((slot * 16) ^ ((row & 7) << 4))) = v;
    }
    __syncthreads();
#pragma unroll
    for (int ks = 0; ks < 2; ++ks) {
      bf16x8 a[4], b[4];
#pragma unroll
      for (int i = 0; i < 4; ++i) {
        int arow = wr * 64 + i * 16 + (lane & 15);
        int akb  = (ks * 64 + (lane >> 4) * 16) ^ ((arow & 7) << 4);
        a[i] = lds_frag(sm, A_OFF + arow * 128 + akb);
        int brow = wc * 64 + i * 16 + (lane & 15);
        int bkb  = (ks * 64 + (lane >> 4) * 16) ^ ((brow & 7) << 4);
        b[i] = lds_frag(sm, B_OFF + brow * 128 + bkb);
      }
#pragma unroll
      for (int i = 0; i < 4; ++i)
#pragma unroll
        for (int jn = 0; jn < 4; ++jn)
          acc[i][jn] = MFMA16(a[i], b[jn], acc[i][jn]);
    }
  }

#pragma unroll
  for (int i = 0; i < 4; ++i)
#pragma unroll
    for (int jn = 0; jn < 4; ++jn) {
      int gcol = bx * 128 + wc * 64 + jn * 16 + (lane & 15);
      float bias = b_ih[gcol];
#pragma unroll
      for (int r4 = 0; r4 < 4; ++r4) {
        int grow = by * 128 + wr * 64 + i * 16 + (lane >> 4) * 4 + r4;
        gi[(size_t)grow * 768 + gcol] = acc[i][jn][r4] + bias;
      }
    }
}

// ---------------------------------------------------------------------------
// Whole GRU in one kernel. 28 blocks x 512 thr (8 waves), 16 seqs per block.
// w_hh B-fragments are STREAMED from the packed global buffer each step
// (L2-hot, coalesced 1 KB/wave loads) — NOT kept resident (that spilled to
// scratch in round 3: 192 VGPR of weights vs RA's 128 target).
// Opaque-pointer asm per step prevents the compiler from re-hoisting the
// loop-invariant loads back into registers.
// ---------------------------------------------------------------------------
__global__ __launch_bounds__(512, 2) void gru_fused(
    const u16* __restrict__ whh_pk, const float* __restrict__ b_hh,
    const float* __restrict__ hidden, const float* __restrict__ gi,
    u16* __restrict__ ctxb)
{
  const int n0 = blockIdx.x * 16;
  const int t = threadIdx.x, lane = t & 63, w = t >> 6;

  __shared__ char sm[74240];
  const int HBF = 0;          // [16][512B] swizzled bf16 h
  const int GH  = 8192;       // [16][776] f32 (pad 8)
  const int HF  = 57856;      // [16][256] f32

  const int pcol = t & 255;   // pointwise column owned by this thread
  const float br = b_hh[pcol], bz = b_hh[256 + pcol], bn = b_hh[512 + pcol];

  // init h: 16 seqs x 256 cols
  {
    float hv = hidden[pcol];
    int s0 = t >> 8;
#pragma unroll
    for (int j = 0; j < 8; ++j) {
      int seq = s0 + j * 2;
      *(float*)(sm + HF + (seq * 256 + pcol) * 4) = hv;
      *(u16*)(sm + HBF + seq * 512 + ((pcol * 2) ^ ((seq & 7) << 4))) = f2bf(hv);
    }
  }

  const int arow = lane & 15;
  for (int r = 0; r < 6; ++r) {
    __syncthreads();  // h (bf16) ready

    uintptr_t pa = (uintptr_t)whh_pk;
    asm volatile("" : "+v"(pa));          // defeat cross-step load hoisting
    const u16* pk = (const u16*)pa;

    f32x4 acc[6];
#pragma unroll
    for (int nf = 0; nf < 6; ++nf) acc[nf] = (f32x4){0.f, 0.f, 0.f, 0.f};
#pragma unroll
    for (int ks = 0; ks < 8; ++ks) {
      bf16x8 a = lds_frag(sm, HBF + arow * 512 +
                          ((ks * 64 + (lane >> 4) * 16) ^ ((arow & 7) << 4)));
#pragma unroll
      for (int nf = 0; nf < 6; ++nf) {
        int cb = w * 6 + nf;
        bf16x8 bb = *(const bf16x8*)&pk[(size_t)(((cb * 8 + ks) * 64) + lane) * 8];
        acc[nf] = MFMA16(a, bb, acc[nf]);
      }
    }
    // gh -> LDS (C/D: col=lane&15, row=(lane>>4)*4+r4)
#pragma unroll
    for (int nf = 0; nf < 6; ++nf) {
      int col = w * 96 + nf * 16 + (lane & 15);
#pragma unroll
      for (int r4 = 0; r4 < 4; ++r4) {
        int row = (lane >> 4) * 4 + r4;
        *(float*)(sm + GH + (row * 776 + col) * 4) = acc[nf][r4];
      }
    }
    __syncthreads();  // gh ready

    // pointwise: thread owns col pcol, seqs (t>>8) + 2*j
    {
      const float* gbase = &gi[((size_t)r * 448 + n0) * 768];
#pragma unroll
      for (int j = 0; j < 8; ++j) {
        int seq = (t >> 8) + j * 2;
        const float* g = gbase + (size_t)seq * 768;
        float ir  = g[pcol];
        float iz  = g[256 + pcol];
        float in_ = g[512 + pcol];
        float ghr = *(const float*)(sm + GH + (seq * 776 + pcol) * 4);
        float ghz = *(const float*)(sm + GH + (seq * 776 + 256 + pcol) * 4);
        float ghn = *(const float*)(sm + GH + (seq * 776 + 512 + pcol) * 4);
        float rg = 1.f / (1.f + expf(-(ir + ghr + br)));
        float zg = 1.f / (1.f + expf(-(iz + ghz + bz)));
        float ng = tanhf(in_ + rg * (ghn + bn));
        float hold = *(const float*)(sm + HF + (seq * 256 + pcol) * 4);
        float hnew = (1.f - zg) * ng + zg * hold;
        *(float*)(sm + HF + (seq * 256 + pcol) * 4) = hnew;
        *(u16*)(sm + HBF + seq * 512 + ((pcol * 2) ^ ((seq & 7) << 4))) = f2bf(hnew);
        ctxb[((size_t)r * 448 + n0 + seq) * 256 + pcol] = f2bf(hnew);
      }
    }
  }
}

// ---------------------------------------------------------------------------
// Fused preds+dots, bf16 MFMA. Block (b, s). (unchanged)
// ---------------------------------------------------------------------------
__global__ __launch_bounds__(256) void fused_pd(
    const u16* __restrict__ ctxb, const u16* __restrict__ wkwb,
    const float* __restrict__ wk_b, const u16* __restrict__ encb,
    float* __restrict__ dots)
{
  const int b = blockIdx.x;      // 0..63
  const int s = blockIdx.y;      // 0..4
  const int Ms = (6 - s) * 7;    // valid rows
  const int t = threadIdx.x;
  const int lane = t & 63, w = t >> 6;

  __shared__ uint4 smem4[71680 / 16];
  char* sm = (char*)smem4;
  const int CTX_OFF = 0, WT_OFF = 24576, ET_OFF = 57344, PT_OFF = 65536;

#pragma unroll
  for (int j = 0; j < 6; ++j) {
    int u = j * 256 + t;
    int row = u >> 5, slot = u & 31;
    int rr = row < Ms ? row : 0;
    int r = rr / 7, c = rr - r * 7;
    uint4 v = *(const uint4*)&ctxb[((size_t)(r * 448 + b * 7 + c)) * 256 + slot * 8];
    int off = row * 512 + ((slot * 16) ^ ((row & 7) << 4));
    *(uint4*)(sm + CTX_OFF + off) = v;
  }
  __syncthreads();

  bf16x8 a1[3][8];
#pragma unroll
  for (int m = 0; m < 3; ++m)
#pragma unroll
    for (int ks = 0; ks < 8; ++ks) {
      int row = m * 16 + (lane & 15);
      int kb  = (ks * 64 + (lane >> 4) * 16) ^ ((row & 7) << 4);
      a1[m][ks] = lds_frag(sm, CTX_OFF + row * 512 + kb);
    }

  f32x4 acc2[3];
#pragma unroll
  for (int m = 0; m < 3; ++m) acc2[m] = (f32x4){0.f, 0.f, 0.f, 0.f};

  for (int ch = 0; ch < 20; ++ch) {
    const int d0 = ch * 64;
    if (ch) __syncthreads();

#pragma unroll
    for (int j = 0; j < 8; ++j) {
      int u = j * 256 + t;
      int row = u >> 5, slot = u & 31;
      uint4 v = *(const uint4*)&wkwb[((size_t)s * 1280 + d0 + row) * 256 + slot * 8];
      int off = row * 512 + ((slot * 16) ^ ((row & 7) << 4));
      *(uint4*)(sm + WT_OFF + off) = v;
    }
#pragma unroll
    for (int j = 0; j < 2; ++j) {
      int u = j * 256 + t;
      int row = u >> 3, slot = u & 7;
      int q = row < 49 ? row : 0;
      uint4 v = *(const uint4*)&encb[((size_t)(b * 49 + q)) * 1280 + d0 + slot * 8];
      int off = row * 128 + ((slot * 16) ^ ((row & 7) << 4));
      *(uint4*)(sm + ET_OFF + off) = v;
    }
    __syncthreads();

    f32x4 acc1[3];
#pragma unroll
    for (int m = 0; m < 3; ++m) acc1[m] = (f32x4){0.f, 0.f, 0.f, 0.f};
#pragma unroll
    for (int ks = 0; ks < 8; ++ks) {
      int row = w * 16 + (lane & 15);
      int kb  = (ks * 64 + (lane >> 4) * 16) ^ ((row & 7) << 4);
      bf16x8 bfrag = lds_frag(sm, WT_OFF + row * 512 + kb);
      acc1[0] = MFMA16(a1[0][ks], bfrag, acc1[0]);
      acc1[1] = MFMA16(a1[1][ks], bfrag, acc1[1]);
      acc1[2] = MFMA16(a1[2][ks], bfrag, acc1[2]);
    }
    {
      int colL = w * 16 + (lane & 15);
      float bias = wk_b[s * 1280 + d0 + colL];
#pragma unroll
      for (int m = 0; m < 3; ++m)
#pragma unroll
        for (int r4 = 0; r4 < 4; ++r4) {
          float p = acc1[m][r4] + bias;
          p = fminf(fmaxf(p, -1.f), 1.f);
          int prow = m * 16 + (lane >> 4) * 4 + r4;
          int off  = prow * 128 + ((colL * 2) ^ ((prow & 7) << 4));
          *(u16*)(sm + PT_OFF + off) = f2bf(p);
        }
    }
    __syncthreads();

#pragma unroll
    for (int ks = 0; ks < 2; ++ks) {
      int erow = w * 16 + (lane & 15);
      int ekb  = (ks * 64 + (lane >> 4) * 16) ^ ((erow & 7) << 4);
      bf16x8 efrag = lds_frag(sm, ET_OFF + erow * 128 + ekb);
#pragma unroll
      for (int m = 0; m < 3; ++m) {
        int prow = m * 16 + (lane & 15);
        int pkb  = (ks * 64 + (lane >> 4) * 16) ^ ((prow & 7) << 4);
        bf16x8 pfrag = lds_frag(sm, PT_OFF + prow * 128 + pkb);
        acc2[m] = MFMA16(pfrag, efrag, acc2[m]);
      }
    }
  }

#pragma unroll
  for (int m = 0; m < 3; ++m)
#pragma unroll
    for (int r4 = 0; r4 < 4; ++r4) {
      int row = m * 16 + (lane >> 4) * 4 + r4;
      int q = w * 16 + (lane & 15);
      if (row < Ms && q < 49)
        dots[((size_t)(b * 5 + s) * 42 + row) * 49 + q] = acc2[m][r4];
    }
}

// ---------------------------------------------------------------------------
// Loss + accuracy over 8960 valid tuples -> accbuf[2]
// ---------------------------------------------------------------------------
__global__ __launch_bounds__(256) void loss_kernel(
    const float* __restrict__ dots, const int* __restrict__ neg_rows,
    const int* __restrict__ neg_cols, float* __restrict__ accbuf)
{
  int gid = blockIdx.x * 256 + threadIdx.x;
  float lsum = 0.f, csum = 0.f;
  if (gid < 8960) {
    int b = gid / 140;
    int rem = gid % 140;
    int p = rem / 7, c = rem % 7;
    int s, r;
    if      (p < 6)  { s = 0; r = p; }
    else if (p < 11) { s = 1; r = p - 6; }
    else if (p < 15) { s = 2; r = p - 11; }
    else if (p < 18) { s = 3; r = p - 15; }
    else             { s = 4; r = p - 18; }

    const float* drow = &dots[((size_t)(b * 5 + s) * 42 + r * 7 + c) * 49];
    float d[17];
    d[0] = drow[r * 7 + c];
    const int nbase = (((b * 5 + s) * 6 + r) * 7 + c) * 16;
#pragma unroll
    for (int j = 0; j < 16; ++j) {
      int q = neg_rows[nbase + j] * 7 + neg_cols[nbase + j];
      d[1 + j] = drow[q];
    }
    float m = d[0];
#pragma unroll
    for (int j = 1; j < 17; ++j) m = fmaxf(m, d[j]);
    float se = 0.f;
#pragma unroll
    for (int j = 0; j < 17; ++j) se += expf(d[j] - m);
    lsum = -(d[0] - m - logf(se));
    csum = (d[0] >= m) ? 1.f : 0.f;
  }

#pragma unroll
  for (int off = 32; off > 0; off >>= 1) {
    lsum += __shfl_down(lsum, off);
    csum += __shfl_down(csum, off);
  }
  __shared__ float red[8];
  int wid = threadIdx.x >> 6;
  if ((threadIdx.x & 63) == 0) { red[wid * 2] = lsum; red[wid * 2 + 1] = csum; }
  __syncthreads();
  if (threadIdx.x == 0) {
    atomicAdd(&accbuf[0], red[0] + red[2] + red[4] + red[6]);
    atomicAdd(&accbuf[1], red[1] + red[3] + red[5] + red[7]);
  }
}

__global__ void finalize(const float* __restrict__ accbuf, float* __restrict__ out)
{
  out[0] = accbuf[0] / 8960.f;
  out[1] = accbuf[1] / 8960.f;
}

// ---------------------------------------------------------------------------
extern "C" void kernel_launch(void* const* d_in, const int* in_sizes, int n_in,
                              void* d_out, int out_size, void* d_ws, size_t ws_size,
                              hipStream_t stream)
{
  const float* enc    = (const float*)d_in[0];
  const float* hidden = (const float*)d_in[1];
  const float* w_ih   = (const float*)d_in[2];
  const float* w_hh   = (const float*)d_in[3];
  const float* b_ih   = (const float*)d_in[4];
  const float* b_hh   = (const float*)d_in[5];
  const float* wk_w   = (const float*)d_in[6];
  const float* wk_b   = (const float*)d_in[7];
  const int* neg_rows = (const int*)d_in[8];
  const int* neg_cols = (const int*)d_in[9];
  float* out = (float*)d_out;

  float* ws    = (float*)d_ws;
  float* accb  = ws;                               // 64 f32
  float* gi    = ws + 64;                          // [6*448][768] f32
  u16*   ctxb  = (u16*)(gi + 6 * 448 * 768);       // [6*448][256] bf16
  u16*   encb  = ctxb + 6 * 448 * 256;             // [64*49][1280] bf16
  u16*   wkwb  = encb + 64 * 49 * 1280;            // [5][1280][256] bf16
  u16*   wihb  = wkwb + 5 * 1280 * 256;            // [768][1280] bf16
  u16*   whhpk = wihb + 768 * 1280;                // [48*8*64*8] bf16 packed
  float* dotsb = (float*)(whhpk + 768 * 256 + 768); // [64][5][42][49] f32

  hipMemsetAsync(accb, 0, 2 * sizeof(float), stream);

  cvt_bf16<<<(64 * 49 * 1280 / 4 + 255) / 256, 256, 0, stream>>>(enc, encb, 64 * 49 * 1280);
  cvt_bf16<<<(5 * 1280 * 256 / 4 + 255) / 256, 256, 0, stream>>>(wk_w, wkwb, 5 * 1280 * 256);
  cvt_bf16<<<(768 * 1280 / 4 + 255) / 256, 256, 0, stream>>>(w_ih, wihb, 768 * 1280);
  pack_whh<<<96, 256, 0, stream>>>(w_hh, whhpk);

  gi_mfma<<<dim3(6, 21), 256, 0, stream>>>(encb, wihb, b_ih, gi);

  gru_fused<<<28, 512, 0, stream>>>(whhpk, b_hh, hidden, gi, ctxb);

  fused_pd<<<dim3(64, 5), 256, 0, stream>>>(ctxb, wkwb, wk_b, encb, dotsb);

  loss_kernel<<<35, 256, 0, stream>>>(dotsb, neg_rows, neg_cols, accb);
  finalize<<<1, 1, 0, stream>>>(accb, out);
}

// Round 5
// 133.074 us; speedup vs baseline: 6.4010x; 1.1739x over previous
//
#include <hip/hip_runtime.h>
#include <math.h>

// B=64, ROWS=7, COLS=7, D=1280, H=256, S=5, NEG=16, GRU_ROWS=6
// valid (s,r): r < 6-s -> 20 pairs; num_preds = 20*64*7 = 8960

typedef __bf16 bf16x8 __attribute__((ext_vector_type(8)));
typedef float  f32x4  __attribute__((ext_vector_type(4)));
typedef unsigned short u16;

__device__ inline u16 f2bf(float f) {           // RNE f32 -> bf16 bits
  unsigned int u = __float_as_uint(f);
  u += 0x7fff + ((u >> 16) & 1);
  return (u16)(u >> 16);
}

__device__ inline bf16x8 lds_frag(const char* sm, int off) {
  return __builtin_bit_cast(bf16x8, *(const uint4*)(sm + off));
}

#define MFMA16(a, b, c) __builtin_amdgcn_mfma_f32_16x16x32_bf16(a, b, c, 0, 0, 0)

// ---------------------------------------------------------------------------
// One-shot f32->bf16 for enc | wk_w | w_ih (three consecutive ranges)
// ---------------------------------------------------------------------------
__global__ __launch_bounds__(256) void cvt3(
    const float* __restrict__ enc, const float* __restrict__ wkw,
    const float* __restrict__ wih,
    u16* __restrict__ encb, u16* __restrict__ wkwb, u16* __restrict__ wihb)
{
  const int N1 = 64 * 49 * 1280;
  const int N2 = N1 + 5 * 1280 * 256;
  const int N3 = N2 + 768 * 1280;
  int i4 = (blockIdx.x * 256 + threadIdx.x) * 4;
  const float* src; u16* dst; int off;
  if (i4 < N1)      { src = enc; dst = encb; off = i4; }
  else if (i4 < N2) { src = wkw; dst = wkwb; off = i4 - N1; }
  else if (i4 < N3) { src = wih; dst = wihb; off = i4 - N2; }
  else return;
  float4 v = *(const float4*)&src[off];
  ushort4 o;
  o.x = f2bf(v.x); o.y = f2bf(v.y); o.z = f2bf(v.z); o.w = f2bf(v.w);
  *(ushort4*)&dst[off] = o;
}

// ---------------------------------------------------------------------------
// Pack w_hh [768][256] f32 -> per-lane MFMA B-fragment order (bf16),
// GATE-INTERLEAVED: fragment cb = w*6 + nf, nf = g*2 + half maps to
// weight col = g*256 + w*32 + half*16 + (lane&15), k = ks*32 + (lane>>4)*8.
// ---------------------------------------------------------------------------
__global__ __launch_bounds__(256) void pack_whh(
    const float* __restrict__ w_hh, u16* __restrict__ pk)
{
  int tid = blockIdx.x * 256 + threadIdx.x;  // 0..24575
  int lane = tid & 63;
  int rest = tid >> 6;                       // cb*8 + ks
  int cb = rest >> 3, ks = rest & 7;
  int w = cb / 6, nf = cb % 6;
  int g = nf >> 1, half = nf & 1;
  int col = g * 256 + w * 32 + half * 16 + (lane & 15);
  int k = ks * 32 + (lane >> 4) * 8;
  const float* src = &w_hh[(size_t)col * 256 + k];
  float4 v0 = *(const float4*)src;
  float4 v1 = *(const float4*)(src + 4);
  u16 o[8] = {f2bf(v0.x), f2bf(v0.y), f2bf(v0.z), f2bf(v0.w),
              f2bf(v1.x), f2bf(v1.y), f2bf(v1.z), f2bf(v1.w)};
  *(uint4*)&pk[(size_t)tid * 8] = *(uint4*)o;
}

// ---------------------------------------------------------------------------
// gi = enc @ w_ih^T + b_ih via bf16 MFMA. (unchanged)
// ---------------------------------------------------------------------------
__global__ __launch_bounds__(256) void gi_mfma(
    const u16* __restrict__ encb, const u16* __restrict__ wihb,
    const float* __restrict__ b_ih, float* __restrict__ gi)
{
  const int bx = blockIdx.x, by = blockIdx.y;
  const int t = threadIdx.x, lane = t & 63, w = t >> 6;
  const int wr = w >> 1, wc = w & 1;

  __shared__ char sm[32768];
  const int A_OFF = 0, B_OFF = 16384;

  f32x4 acc[4][4];
#pragma unroll
  for (int i = 0; i < 4; ++i)
#pragma unroll
    for (int j = 0; j < 4; ++j) acc[i][j] = (f32x4){0.f, 0.f, 0.f, 0.f};

  for (int k0 = 0; k0 < 1280; k0 += 64) {
    if (k0) __syncthreads();
#pragma unroll
    for (int j = 0; j < 4; ++j) {
      int u = j * 256 + t;
      int row = u >> 3, slot = u & 7;
      int m = by * 128 + row;
      int r = m / 448, n = m - r * 448;
      int b = n / 7, c = n - b * 7;
      uint4 v = *(const uint4*)&encb[(size_t)(b * 49 + r * 7 + c) * 1280 + k0 + slot * 8];
      *(uint4*)(sm + A_OFF + row * 128 + ((slot * 16) ^ ((row & 7) << 4))) = v;
    }
#pragma unroll
    for (int j = 0; j < 4; ++j) {
      int u = j * 256 + t;
      int row = u >> 3, slot = u & 7;
      uint4 v = *(const uint4*)&wihb[(size_t)(bx * 128 + row) * 1280 + k0 + slot * 8];
      *(uint4*)(sm + B_OFF + row * 128 + ((slot * 16) ^ ((row & 7) << 4))) = v;
    }
    __syncthreads();
#pragma unroll
    for (int ks = 0; ks < 2; ++ks) {
      bf16x8 a[4], b[4];
#pragma unroll
      for (int i = 0; i < 4; ++i) {
        int arow = wr * 64 + i * 16 + (lane & 15);
        int akb  = (ks * 64 + (lane >> 4) * 16) ^ ((arow & 7) << 4);
        a[i] = lds_frag(sm, A_OFF + arow * 128 + akb);
        int brow = wc * 64 + i * 16 + (lane & 15);
        int bkb  = (ks * 64 + (lane >> 4) * 16) ^ ((brow & 7) << 4);
        b[i] = lds_frag(sm, B_OFF + brow * 128 + bkb);
      }
#pragma unroll
      for (int i = 0; i < 4; ++i)
#pragma unroll
        for (int jn = 0; jn < 4; ++jn)
          acc[i][jn] = MFMA16(a[i], b[jn], acc[i][jn]);
    }
  }

#pragma unroll
  for (int i = 0; i < 4; ++i)
#pragma unroll
    for (int jn = 0; jn < 4; ++jn) {
      int gcol = bx * 128 + wc * 64 + jn * 16 + (lane & 15);
      float bias = b_ih[gcol];
#pragma unroll
      for (int r4 = 0; r4 < 4; ++r4) {
        int grow = by * 128 + wr * 64 + i * 16 + (lane >> 4) * 4 + r4;
        gi[(size_t)grow * 768 + gcol] = acc[i][jn][r4] + bias;
      }
    }
}

// ---------------------------------------------------------------------------
// GRU, one kernel, 28 blocks x 512 thr (8 waves), 16 seqs/block.
// Gate-interleaved packing -> pointwise fully in registers, h ("hold")
// persistent in registers, ONE barrier/step, double-buffered bf16 h in LDS.
// Weights: nf 0..3 resident in VGPRs; nf 4..5 streamed (opaque ptr).
// ---------------------------------------------------------------------------
__global__ __launch_bounds__(512, 1) void gru_fused(
    const u16* __restrict__ whh_pk, const float* __restrict__ b_hh,
    const float* __restrict__ hidden, const float* __restrict__ gi,
    u16* __restrict__ ctxb)
{
  const int n0 = blockIdx.x * 16;
  const int t = threadIdx.x, lane = t & 63, w = t >> 6;

  __shared__ uint4 smem4[16384 / 16];   // two 8KB swizzled bf16 h buffers
  char* sm = (char*)smem4;

  const int l15 = lane & 15;
  const int seq0 = (lane >> 4) * 4;
  const int hc0 = w * 32 + l15, hc1 = w * 32 + 16 + l15;

  float br0 = b_hh[hc0],       br1 = b_hh[hc1];
  float bz0 = b_hh[256 + hc0], bz1 = b_hh[256 + hc1];
  float bn0 = b_hh[512 + hc0], bn1 = b_hh[512 + hc1];

  bf16x8 wres[4][8];
#pragma unroll
  for (int nf = 0; nf < 4; ++nf)
#pragma unroll
    for (int ks = 0; ks < 8; ++ks)
      wres[nf][ks] = *(const bf16x8*)&whh_pk[(size_t)(((w * 6 + nf) * 8 + ks) * 64 + lane) * 8];

  float hold[2][4];
  {
    float h0 = hidden[hc0], h1 = hidden[hc1];
#pragma unroll
    for (int r4 = 0; r4 < 4; ++r4) { hold[0][r4] = h0; hold[1][r4] = h1; }
    u16 hb0 = f2bf(h0), hb1 = f2bf(h1);
#pragma unroll
    for (int r4 = 0; r4 < 4; ++r4) {
      int seq = seq0 + r4;
      *(u16*)(sm + seq * 512 + ((hc0 * 2) ^ ((seq & 7) << 4))) = hb0;
      *(u16*)(sm + seq * 512 + ((hc1 * 2) ^ ((seq & 7) << 4))) = hb1;
    }
  }
  __syncthreads();

  for (int r = 0; r < 6; ++r) {
    const char* hb = sm + (r & 1) * 8192;
    char* hbn = sm + ((r + 1) & 1) * 8192;

    // gi loads (h-independent): issued at step top, overlap MFMA phase
    float giv[3][2][4];
    {
      const float* gbase = &gi[(size_t)(r * 448 + n0 + seq0) * 768];
#pragma unroll
      for (int g = 0; g < 3; ++g)
#pragma unroll
        for (int r4 = 0; r4 < 4; ++r4) {
          giv[g][0][r4] = gbase[(size_t)r4 * 768 + g * 256 + hc0];
          giv[g][1][r4] = gbase[(size_t)r4 * 768 + g * 256 + hc1];
        }
    }

    uintptr_t pa = (uintptr_t)whh_pk;
    asm volatile("" : "+v"(pa));        // defeat cross-step load hoisting
    const u16* pk = (const u16*)pa;

    f32x4 acc[6];
#pragma unroll
    for (int nf = 0; nf < 6; ++nf) acc[nf] = (f32x4){0.f, 0.f, 0.f, 0.f};
#pragma unroll
    for (int ks = 0; ks < 8; ++ks) {
      bf16x8 a = lds_frag(hb, l15 * 512 +
                          ((ks * 64 + (lane >> 4) * 16) ^ ((l15 & 7) << 4)));
      bf16x8 b4 = *(const bf16x8*)&pk[(size_t)(((w * 6 + 4) * 8 + ks) * 64 + lane) * 8];
      bf16x8 b5 = *(const bf16x8*)&pk[(size_t)(((w * 6 + 5) * 8 + ks) * 64 + lane) * 8];
      acc[0] = MFMA16(a, wres[0][ks], acc[0]);
      acc[1] = MFMA16(a, wres[1][ks], acc[1]);
      acc[2] = MFMA16(a, wres[2][ks], acc[2]);
      acc[3] = MFMA16(a, wres[3][ks], acc[3]);
      acc[4] = MFMA16(a, b4, acc[4]);
      acc[5] = MFMA16(a, b5, acc[5]);
    }

    // pointwise in registers: acc[0+half]=r, acc[2+half]=z, acc[4+half]=n
#pragma unroll
    for (int r4 = 0; r4 < 4; ++r4) {
      int seq = seq0 + r4;
      {
        float rg = 1.f / (1.f + expf(-(giv[0][0][r4] + acc[0][r4] + br0)));
        float zg = 1.f / (1.f + expf(-(giv[1][0][r4] + acc[2][r4] + bz0)));
        float ng = tanhf(giv[2][0][r4] + rg * (acc[4][r4] + bn0));
        float hnew = (1.f - zg) * ng + zg * hold[0][r4];
        hold[0][r4] = hnew;
        u16 hb16 = f2bf(hnew);
        *(u16*)(hbn + seq * 512 + ((hc0 * 2) ^ ((seq & 7) << 4))) = hb16;
        ctxb[(size_t)(r * 448 + n0 + seq) * 256 + hc0] = hb16;
      }
      {
        float rg = 1.f / (1.f + expf(-(giv[0][1][r4] + acc[1][r4] + br1)));
        float zg = 1.f / (1.f + expf(-(giv[1][1][r4] + acc[3][r4] + bz1)));
        float ng = tanhf(giv[2][1][r4] + rg * (acc[5][r4] + bn1));
        float hnew = (1.f - zg) * ng + zg * hold[1][r4];
        hold[1][r4] = hnew;
        u16 hb16 = f2bf(hnew);
        *(u16*)(hbn + seq * 512 + ((hc1 * 2) ^ ((seq & 7) << 4))) = hb16;
        ctxb[(size_t)(r * 448 + n0 + seq) * 256 + hc1] = hb16;
      }
    }
    __syncthreads();
  }
}

// ---------------------------------------------------------------------------
// Fused preds+dots, bf16 MFMA. Block (b, s). (unchanged)
// ---------------------------------------------------------------------------
__global__ __launch_bounds__(256) void fused_pd(
    const u16* __restrict__ ctxb, const u16* __restrict__ wkwb,
    const float* __restrict__ wk_b, const u16* __restrict__ encb,
    float* __restrict__ dots)
{
  const int b = blockIdx.x;
  const int s = blockIdx.y;
  const int Ms = (6 - s) * 7;
  const int t = threadIdx.x;
  const int lane = t & 63, w = t >> 6;

  __shared__ uint4 smem4[71680 / 16];
  char* sm = (char*)smem4;
  const int CTX_OFF = 0, WT_OFF = 24576, ET_OFF = 57344, PT_OFF = 65536;

#pragma unroll
  for (int j = 0; j < 6; ++j) {
    int u = j * 256 + t;
    int row = u >> 5, slot = u & 31;
    int rr = row < Ms ? row : 0;
    int r = rr / 7, c = rr - r * 7;
    uint4 v = *(const uint4*)&ctxb[((size_t)(r * 448 + b * 7 + c)) * 256 + slot * 8];
    int off = row * 512 + ((slot * 16) ^ ((row & 7) << 4));
    *(uint4*)(sm + CTX_OFF + off) = v;
  }
  __syncthreads();

  bf16x8 a1[3][8];
#pragma unroll
  for (int m = 0; m < 3; ++m)
#pragma unroll
    for (int ks = 0; ks < 8; ++ks) {
      int row = m * 16 + (lane & 15);
      int kb  = (ks * 64 + (lane >> 4) * 16) ^ ((row & 7) << 4);
      a1[m][ks] = lds_frag(sm, CTX_OFF + row * 512 + kb);
    }

  f32x4 acc2[3];
#pragma unroll
  for (int m = 0; m < 3; ++m) acc2[m] = (f32x4){0.f, 0.f, 0.f, 0.f};

  for (int ch = 0; ch < 20; ++ch) {
    const int d0 = ch * 64;
    if (ch) __syncthreads();

#pragma unroll
    for (int j = 0; j < 8; ++j) {
      int u = j * 256 + t;
      int row = u >> 5, slot = u & 31;
      uint4 v = *(const uint4*)&wkwb[((size_t)s * 1280 + d0 + row) * 256 + slot * 8];
      int off = row * 512 + ((slot * 16) ^ ((row & 7) << 4));
      *(uint4*)(sm + WT_OFF + off) = v;
    }
#pragma unroll
    for (int j = 0; j < 2; ++j) {
      int u = j * 256 + t;
      int row = u >> 3, slot = u & 7;
      int q = row < 49 ? row : 0;
      uint4 v = *(const uint4*)&encb[((size_t)(b * 49 + q)) * 1280 + d0 + slot * 8];
      int off = row * 128 + ((slot * 16) ^ ((row & 7) << 4));
      *(uint4*)(sm + ET_OFF + off) = v;
    }
    __syncthreads();

    f32x4 acc1[3];
#pragma unroll
    for (int m = 0; m < 3; ++m) acc1[m] = (f32x4){0.f, 0.f, 0.f, 0.f};
#pragma unroll
    for (int ks = 0; ks < 8; ++ks) {
      int row = w * 16 + (lane & 15);
      int kb  = (ks * 64 + (lane >> 4) * 16) ^ ((row & 7) << 4);
      bf16x8 bfrag = lds_frag(sm, WT_OFF + row * 512 + kb);
      acc1[0] = MFMA16(a1[0][ks], bfrag, acc1[0]);
      acc1[1] = MFMA16(a1[1][ks], bfrag, acc1[1]);
      acc1[2] = MFMA16(a1[2][ks], bfrag, acc1[2]);
    }
    {
      int colL = w * 16 + (lane & 15);
      float bias = wk_b[s * 1280 + d0 + colL];
#pragma unroll
      for (int m = 0; m < 3; ++m)
#pragma unroll
        for (int r4 = 0; r4 < 4; ++r4) {
          float p = acc1[m][r4] + bias;
          p = fminf(fmaxf(p, -1.f), 1.f);
          int prow = m * 16 + (lane >> 4) * 4 + r4;
          int off  = prow * 128 + ((colL * 2) ^ ((prow & 7) << 4));
          *(u16*)(sm + PT_OFF + off) = f2bf(p);
        }
    }
    __syncthreads();

#pragma unroll
    for (int ks = 0; ks < 2; ++ks) {
      int erow = w * 16 + (lane & 15);
      int ekb  = (ks * 64 + (lane >> 4) * 16) ^ ((erow & 7) << 4);
      bf16x8 efrag = lds_frag(sm, ET_OFF + erow * 128 + ekb);
#pragma unroll
      for (int m = 0; m < 3; ++m) {
        int prow = m * 16 + (lane & 15);
        int pkb  = (ks * 64 + (lane >> 4) * 16) ^ ((prow & 7) << 4);
        bf16x8 pfrag = lds_frag(sm, PT_OFF + prow * 128 + pkb);
        acc2[m] = MFMA16(pfrag, efrag, acc2[m]);
      }
    }
  }

#pragma unroll
  for (int m = 0; m < 3; ++m)
#pragma unroll
    for (int r4 = 0; r4 < 4; ++r4) {
      int row = m * 16 + (lane >> 4) * 4 + r4;
      int q = w * 16 + (lane & 15);
      if (row < Ms && q < 49)
        dots[((size_t)(b * 5 + s) * 42 + row) * 49 + q] = acc2[m][r4];
    }
}

// ---------------------------------------------------------------------------
// Loss + accuracy -> directly into d_out[2] (pre-zeroed), scaled by 1/8960
// ---------------------------------------------------------------------------
__global__ __launch_bounds__(256) void loss_kernel(
    const float* __restrict__ dots, const int* __restrict__ neg_rows,
    const int* __restrict__ neg_cols, float* __restrict__ out)
{
  int gid = blockIdx.x * 256 + threadIdx.x;
  float lsum = 0.f, csum = 0.f;
  if (gid < 8960) {
    int b = gid / 140;
    int rem = gid % 140;
    int p = rem / 7, c = rem % 7;
    int s, r;
    if      (p < 6)  { s = 0; r = p; }
    else if (p < 11) { s = 1; r = p - 6; }
    else if (p < 15) { s = 2; r = p - 11; }
    else if (p < 18) { s = 3; r = p - 15; }
    else             { s = 4; r = p - 18; }

    const float* drow = &dots[((size_t)(b * 5 + s) * 42 + r * 7 + c) * 49];
    float d[17];
    d[0] = drow[r * 7 + c];
    const int nbase = (((b * 5 + s) * 6 + r) * 7 + c) * 16;
#pragma unroll
    for (int j = 0; j < 16; ++j) {
      int q = neg_rows[nbase + j] * 7 + neg_cols[nbase + j];
      d[1 + j] = drow[q];
    }
    float m = d[0];
#pragma unroll
    for (int j = 1; j < 17; ++j) m = fmaxf(m, d[j]);
    float se = 0.f;
#pragma unroll
    for (int j = 0; j < 17; ++j) se += expf(d[j] - m);
    lsum = -(d[0] - m - logf(se));
    csum = (d[0] >= m) ? 1.f : 0.f;
  }

#pragma unroll
  for (int off = 32; off > 0; off >>= 1) {
    lsum += __shfl_down(lsum, off);
    csum += __shfl_down(csum, off);
  }
  __shared__ float red[8];
  int wid = threadIdx.x >> 6;
  if ((threadIdx.x & 63) == 0) { red[wid * 2] = lsum; red[wid * 2 + 1] = csum; }
  __syncthreads();
  if (threadIdx.x == 0) {
    atomicAdd(&out[0], (red[0] + red[2] + red[4] + red[6]) * (1.f / 8960.f));
    atomicAdd(&out[1], (red[1] + red[3] + red[5] + red[7]) * (1.f / 8960.f));
  }
}

// ---------------------------------------------------------------------------
extern "C" void kernel_launch(void* const* d_in, const int* in_sizes, int n_in,
                              void* d_out, int out_size, void* d_ws, size_t ws_size,
                              hipStream_t stream)
{
  const float* enc    = (const float*)d_in[0];
  const float* hidden = (const float*)d_in[1];
  const float* w_ih   = (const float*)d_in[2];
  const float* w_hh   = (const float*)d_in[3];
  const float* b_ih   = (const float*)d_in[4];
  const float* b_hh   = (const float*)d_in[5];
  const float* wk_w   = (const float*)d_in[6];
  const float* wk_b   = (const float*)d_in[7];
  const int* neg_rows = (const int*)d_in[8];
  const int* neg_cols = (const int*)d_in[9];
  float* out = (float*)d_out;

  float* ws    = (float*)d_ws;
  float* gi    = ws;                                // [6*448][768] f32
  u16*   ctxb  = (u16*)(gi + 6 * 448 * 768);        // [6*448][256] bf16
  u16*   encb  = ctxb + 6 * 448 * 256;              // [64*49][1280] bf16
  u16*   wkwb  = encb + 64 * 49 * 1280;             // [5][1280][256] bf16
  u16*   wihb  = wkwb + 5 * 1280 * 256;             // [768][1280] bf16
  u16*   whhpk = wihb + 768 * 1280;                 // [48*8*64*8] bf16 packed
  float* dotsb = (float*)(whhpk + 768 * 256 + 768); // [64][5][42][49] f32

  hipMemsetAsync(out, 0, 2 * sizeof(float), stream);

  cvt3<<<6482, 256, 0, stream>>>(enc, wk_w, w_ih, encb, wkwb, wihb);
  pack_whh<<<96, 256, 0, stream>>>(w_hh, whhpk);

  gi_mfma<<<dim3(6, 21), 256, 0, stream>>>(encb, wihb, b_ih, gi);

  gru_fused<<<28, 512, 0, stream>>>(whhpk, b_hh, hidden, gi, ctxb);

  fused_pd<<<dim3(64, 5), 256, 0, stream>>>(ctxb, wkwb, wk_b, encb, dotsb);

  loss_kernel<<<35, 256, 0, stream>>>(dotsb, neg_rows, neg_cols, out);
}

// Round 6
// 132.729 us; speedup vs baseline: 6.4176x; 1.0026x over previous
//
#include <hip/hip_runtime.h>
#include <math.h>

// B=64, ROWS=7, COLS=7, D=1280, H=256, S=5, NEG=16, GRU_ROWS=6
// valid (s,r): r < 6-s -> 20 pairs; num_preds = 20*64*7 = 8960

typedef __bf16 bf16x8 __attribute__((ext_vector_type(8)));
typedef float  f32x4  __attribute__((ext_vector_type(4)));
typedef unsigned short u16;

__device__ inline u16 f2bf(float f) {           // RNE f32 -> bf16 bits
  unsigned int u = __float_as_uint(f);
  u += 0x7fff + ((u >> 16) & 1);
  return (u16)(u >> 16);
}

__device__ inline bf16x8 lds_frag(const char* sm, int off) {
  return __builtin_bit_cast(bf16x8, *(const uint4*)(sm + off));
}

#define MFMA16(a, b, c) __builtin_amdgcn_mfma_f32_16x16x32_bf16(a, b, c, 0, 0, 0)

// ---------------------------------------------------------------------------
// One-shot f32->bf16 for enc | wk_w | w_ih (three consecutive ranges)
// ---------------------------------------------------------------------------
__global__ __launch_bounds__(256) void cvt3(
    const float* __restrict__ enc, const float* __restrict__ wkw,
    const float* __restrict__ wih,
    u16* __restrict__ encb, u16* __restrict__ wkwb, u16* __restrict__ wihb)
{
  const int N1 = 64 * 49 * 1280;
  const int N2 = N1 + 5 * 1280 * 256;
  const int N3 = N2 + 768 * 1280;
  int i4 = (blockIdx.x * 256 + threadIdx.x) * 4;
  const float* src; u16* dst; int off;
  if (i4 < N1)      { src = enc; dst = encb; off = i4; }
  else if (i4 < N2) { src = wkw; dst = wkwb; off = i4 - N1; }
  else if (i4 < N3) { src = wih; dst = wihb; off = i4 - N2; }
  else return;
  float4 v = *(const float4*)&src[off];
  ushort4 o;
  o.x = f2bf(v.x); o.y = f2bf(v.y); o.z = f2bf(v.z); o.w = f2bf(v.w);
  *(ushort4*)&dst[off] = o;
}

// ---------------------------------------------------------------------------
// Pack w_hh [768][256] f32 -> per-lane MFMA B-fragment order (bf16),
// GATE-INTERLEAVED: fragment cb = w*6 + nf, nf = g*2 + half maps to
// weight col = g*256 + w*32 + half*16 + (lane&15), k = ks*32 + (lane>>4)*8.
// ---------------------------------------------------------------------------
__global__ __launch_bounds__(256) void pack_whh(
    const float* __restrict__ w_hh, u16* __restrict__ pk)
{
  int tid = blockIdx.x * 256 + threadIdx.x;  // 0..24575
  int lane = tid & 63;
  int rest = tid >> 6;                       // cb*8 + ks
  int cb = rest >> 3, ks = rest & 7;
  int w = cb / 6, nf = cb % 6;
  int g = nf >> 1, half = nf & 1;
  int col = g * 256 + w * 32 + half * 16 + (lane & 15);
  int k = ks * 32 + (lane >> 4) * 8;
  const float* src = &w_hh[(size_t)col * 256 + k];
  float4 v0 = *(const float4*)src;
  float4 v1 = *(const float4*)(src + 4);
  u16 o[8] = {f2bf(v0.x), f2bf(v0.y), f2bf(v0.z), f2bf(v0.w),
              f2bf(v1.x), f2bf(v1.y), f2bf(v1.z), f2bf(v1.w)};
  *(uint4*)&pk[(size_t)tid * 8] = *(uint4*)o;
}

// ---------------------------------------------------------------------------
// gi = enc @ w_ih^T + b_ih via bf16 MFMA. (unchanged)
// ---------------------------------------------------------------------------
__global__ __launch_bounds__(256) void gi_mfma(
    const u16* __restrict__ encb, const u16* __restrict__ wihb,
    const float* __restrict__ b_ih, float* __restrict__ gi)
{
  const int bx = blockIdx.x, by = blockIdx.y;
  const int t = threadIdx.x, lane = t & 63, w = t >> 6;
  const int wr = w >> 1, wc = w & 1;

  __shared__ char sm[32768];
  const int A_OFF = 0, B_OFF = 16384;

  f32x4 acc[4][4];
#pragma unroll
  for (int i = 0; i < 4; ++i)
#pragma unroll
    for (int j = 0; j < 4; ++j) acc[i][j] = (f32x4){0.f, 0.f, 0.f, 0.f};

  for (int k0 = 0; k0 < 1280; k0 += 64) {
    if (k0) __syncthreads();
#pragma unroll
    for (int j = 0; j < 4; ++j) {
      int u = j * 256 + t;
      int row = u >> 3, slot = u & 7;
      int m = by * 128 + row;
      int r = m / 448, n = m - r * 448;
      int b = n / 7, c = n - b * 7;
      uint4 v = *(const uint4*)&encb[(size_t)(b * 49 + r * 7 + c) * 1280 + k0 + slot * 8];
      *(uint4*)(sm + A_OFF + row * 128 + ((slot * 16) ^ ((row & 7) << 4))) = v;
    }
#pragma unroll
    for (int j = 0; j < 4; ++j) {
      int u = j * 256 + t;
      int row = u >> 3, slot = u & 7;
      uint4 v = *(const uint4*)&wihb[(size_t)(bx * 128 + row) * 1280 + k0 + slot * 8];
      *(uint4*)(sm + B_OFF + row * 128 + ((slot * 16) ^ ((row & 7) << 4))) = v;
    }
    __syncthreads();
#pragma unroll
    for (int ks = 0; ks < 2; ++ks) {
      bf16x8 a[4], b[4];
#pragma unroll
      for (int i = 0; i < 4; ++i) {
        int arow = wr * 64 + i * 16 + (lane & 15);
        int akb  = (ks * 64 + (lane >> 4) * 16) ^ ((arow & 7) << 4);
        a[i] = lds_frag(sm, A_OFF + arow * 128 + akb);
        int brow = wc * 64 + i * 16 + (lane & 15);
        int bkb  = (ks * 64 + (lane >> 4) * 16) ^ ((brow & 7) << 4);
        b[i] = lds_frag(sm, B_OFF + brow * 128 + bkb);
      }
#pragma unroll
      for (int i = 0; i < 4; ++i)
#pragma unroll
        for (int jn = 0; jn < 4; ++jn)
          acc[i][jn] = MFMA16(a[i], b[jn], acc[i][jn]);
    }
  }

#pragma unroll
  for (int i = 0; i < 4; ++i)
#pragma unroll
    for (int jn = 0; jn < 4; ++jn) {
      int gcol = bx * 128 + wc * 64 + jn * 16 + (lane & 15);
      float bias = b_ih[gcol];
#pragma unroll
      for (int r4 = 0; r4 < 4; ++r4) {
        int grow = by * 128 + wr * 64 + i * 16 + (lane >> 4) * 4 + r4;
        gi[(size_t)grow * 768 + gcol] = acc[i][jn][r4] + bias;
      }
    }
}

// ---------------------------------------------------------------------------
// GRU, one kernel, 28 blocks x 512 thr (8 waves), 16 seqs/block.
// Gate-interleaved packing -> pointwise fully in registers, h ("hold")
// persistent in registers, ONE barrier/step, double-buffered bf16 h in LDS.
// Weights: nf 0..3 resident in VGPRs; nf 4..5 streamed (opaque ptr).
// amdgpu_waves_per_eu(2,2): pin max 2 waves/EU -> 256-VGPR RA budget so the
// 128-VGPR resident weight block does NOT spill (launch_bounds' 2nd arg is
// only a MIN; rounds 3/5 showed the RA otherwise targets 128 and spills).
// ---------------------------------------------------------------------------
__global__ __launch_bounds__(512)
__attribute__((amdgpu_waves_per_eu(2, 2)))
void gru_fused(
    const u16* __restrict__ whh_pk, const float* __restrict__ b_hh,
    const float* __restrict__ hidden, const float* __restrict__ gi,
    u16* __restrict__ ctxb)
{
  const int n0 = blockIdx.x * 16;
  const int t = threadIdx.x, lane = t & 63, w = t >> 6;

  __shared__ uint4 smem4[16384 / 16];   // two 8KB swizzled bf16 h buffers
  char* sm = (char*)smem4;

  const int l15 = lane & 15;
  const int seq0 = (lane >> 4) * 4;
  const int hc0 = w * 32 + l15, hc1 = w * 32 + 16 + l15;

  float br0 = b_hh[hc0],       br1 = b_hh[hc1];
  float bz0 = b_hh[256 + hc0], bz1 = b_hh[256 + hc1];
  float bn0 = b_hh[512 + hc0], bn1 = b_hh[512 + hc1];

  bf16x8 wres[4][8];
#pragma unroll
  for (int nf = 0; nf < 4; ++nf)
#pragma unroll
    for (int ks = 0; ks < 8; ++ks)
      wres[nf][ks] = *(const bf16x8*)&whh_pk[(size_t)(((w * 6 + nf) * 8 + ks) * 64 + lane) * 8];

  float hold[2][4];
  {
    float h0 = hidden[hc0], h1 = hidden[hc1];
#pragma unroll
    for (int r4 = 0; r4 < 4; ++r4) { hold[0][r4] = h0; hold[1][r4] = h1; }
    u16 hb0 = f2bf(h0), hb1 = f2bf(h1);
#pragma unroll
    for (int r4 = 0; r4 < 4; ++r4) {
      int seq = seq0 + r4;
      *(u16*)(sm + seq * 512 + ((hc0 * 2) ^ ((seq & 7) << 4))) = hb0;
      *(u16*)(sm + seq * 512 + ((hc1 * 2) ^ ((seq & 7) << 4))) = hb1;
    }
  }
  __syncthreads();

  for (int r = 0; r < 6; ++r) {
    const char* hb = sm + (r & 1) * 8192;
    char* hbn = sm + ((r + 1) & 1) * 8192;

    // gi loads (h-independent): issued at step top, overlap MFMA phase
    float giv[3][2][4];
    {
      const float* gbase = &gi[(size_t)(r * 448 + n0 + seq0) * 768];
#pragma unroll
      for (int g = 0; g < 3; ++g)
#pragma unroll
        for (int r4 = 0; r4 < 4; ++r4) {
          giv[g][0][r4] = gbase[(size_t)r4 * 768 + g * 256 + hc0];
          giv[g][1][r4] = gbase[(size_t)r4 * 768 + g * 256 + hc1];
        }
    }

    uintptr_t pa = (uintptr_t)whh_pk;
    asm volatile("" : "+v"(pa));        // defeat cross-step load hoisting
    const u16* pk = (const u16*)pa;

    f32x4 acc[6];
#pragma unroll
    for (int nf = 0; nf < 6; ++nf) acc[nf] = (f32x4){0.f, 0.f, 0.f, 0.f};
#pragma unroll
    for (int ks = 0; ks < 8; ++ks) {
      bf16x8 a = lds_frag(hb, l15 * 512 +
                          ((ks * 64 + (lane >> 4) * 16) ^ ((l15 & 7) << 4)));
      bf16x8 b4 = *(const bf16x8*)&pk[(size_t)(((w * 6 + 4) * 8 + ks) * 64 + lane) * 8];
      bf16x8 b5 = *(const bf16x8*)&pk[(size_t)(((w * 6 + 5) * 8 + ks) * 64 + lane) * 8];
      acc[0] = MFMA16(a, wres[0][ks], acc[0]);
      acc[1] = MFMA16(a, wres[1][ks], acc[1]);
      acc[2] = MFMA16(a, wres[2][ks], acc[2]);
      acc[3] = MFMA16(a, wres[3][ks], acc[3]);
      acc[4] = MFMA16(a, b4, acc[4]);
      acc[5] = MFMA16(a, b5, acc[5]);
    }

    // pointwise in registers: acc[0+half]=r, acc[2+half]=z, acc[4+half]=n
#pragma unroll
    for (int r4 = 0; r4 < 4; ++r4) {
      int seq = seq0 + r4;
      {
        float rg = 1.f / (1.f + expf(-(giv[0][0][r4] + acc[0][r4] + br0)));
        float zg = 1.f / (1.f + expf(-(giv[1][0][r4] + acc[2][r4] + bz0)));
        float ng = tanhf(giv[2][0][r4] + rg * (acc[4][r4] + bn0));
        float hnew = (1.f - zg) * ng + zg * hold[0][r4];
        hold[0][r4] = hnew;
        u16 hb16 = f2bf(hnew);
        *(u16*)(hbn + seq * 512 + ((hc0 * 2) ^ ((seq & 7) << 4))) = hb16;
        ctxb[(size_t)(r * 448 + n0 + seq) * 256 + hc0] = hb16;
      }
      {
        float rg = 1.f / (1.f + expf(-(giv[0][1][r4] + acc[1][r4] + br1)));
        float zg = 1.f / (1.f + expf(-(giv[1][1][r4] + acc[3][r4] + bz1)));
        float ng = tanhf(giv[2][1][r4] + rg * (acc[5][r4] + bn1));
        float hnew = (1.f - zg) * ng + zg * hold[1][r4];
        hold[1][r4] = hnew;
        u16 hb16 = f2bf(hnew);
        *(u16*)(hbn + seq * 512 + ((hc1 * 2) ^ ((seq & 7) << 4))) = hb16;
        ctxb[(size_t)(r * 448 + n0 + seq) * 256 + hc1] = hb16;
      }
    }
    __syncthreads();
  }
}

// ---------------------------------------------------------------------------
// Fused preds+dots, bf16 MFMA. Block (b, s). (unchanged)
// ---------------------------------------------------------------------------
__global__ __launch_bounds__(256) void fused_pd(
    const u16* __restrict__ ctxb, const u16* __restrict__ wkwb,
    const float* __restrict__ wk_b, const u16* __restrict__ encb,
    float* __restrict__ dots)
{
  const int b = blockIdx.x;
  const int s = blockIdx.y;
  const int Ms = (6 - s) * 7;
  const int t = threadIdx.x;
  const int lane = t & 63, w = t >> 6;

  __shared__ uint4 smem4[71680 / 16];
  char* sm = (char*)smem4;
  const int CTX_OFF = 0, WT_OFF = 24576, ET_OFF = 57344, PT_OFF = 65536;

#pragma unroll
  for (int j = 0; j < 6; ++j) {
    int u = j * 256 + t;
    int row = u >> 5, slot = u & 31;
    int rr = row < Ms ? row : 0;
    int r = rr / 7, c = rr - r * 7;
    uint4 v = *(const uint4*)&ctxb[((size_t)(r * 448 + b * 7 + c)) * 256 + slot * 8];
    int off = row * 512 + ((slot * 16) ^ ((row & 7) << 4));
    *(uint4*)(sm + CTX_OFF + off) = v;
  }
  __syncthreads();

  bf16x8 a1[3][8];
#pragma unroll
  for (int m = 0; m < 3; ++m)
#pragma unroll
    for (int ks = 0; ks < 8; ++ks) {
      int row = m * 16 + (lane & 15);
      int kb  = (ks * 64 + (lane >> 4) * 16) ^ ((row & 7) << 4);
      a1[m][ks] = lds_frag(sm, CTX_OFF + row * 512 + kb);
    }

  f32x4 acc2[3];
#pragma unroll
  for (int m = 0; m < 3; ++m) acc2[m] = (f32x4){0.f, 0.f, 0.f, 0.f};

  for (int ch = 0; ch < 20; ++ch) {
    const int d0 = ch * 64;
    if (ch) __syncthreads();

#pragma unroll
    for (int j = 0; j < 8; ++j) {
      int u = j * 256 + t;
      int row = u >> 5, slot = u & 31;
      uint4 v = *(const uint4*)&wkwb[((size_t)s * 1280 + d0 + row) * 256 + slot * 8];
      int off = row * 512 + ((slot * 16) ^ ((row & 7) << 4));
      *(uint4*)(sm + WT_OFF + off) = v;
    }
#pragma unroll
    for (int j = 0; j < 2; ++j) {
      int u = j * 256 + t;
      int row = u >> 3, slot = u & 7;
      int q = row < 49 ? row : 0;
      uint4 v = *(const uint4*)&encb[((size_t)(b * 49 + q)) * 1280 + d0 + slot * 8];
      int off = row * 128 + ((slot * 16) ^ ((row & 7) << 4));
      *(uint4*)(sm + ET_OFF + off) = v;
    }
    __syncthreads();

    f32x4 acc1[3];
#pragma unroll
    for (int m = 0; m < 3; ++m) acc1[m] = (f32x4){0.f, 0.f, 0.f, 0.f};
#pragma unroll
    for (int ks = 0; ks < 8; ++ks) {
      int row = w * 16 + (lane & 15);
      int kb  = (ks * 64 + (lane >> 4) * 16) ^ ((row & 7) << 4);
      bf16x8 bfrag = lds_frag(sm, WT_OFF + row * 512 + kb);
      acc1[0] = MFMA16(a1[0][ks], bfrag, acc1[0]);
      acc1[1] = MFMA16(a1[1][ks], bfrag, acc1[1]);
      acc1[2] = MFMA16(a1[2][ks], bfrag, acc1[2]);
    }
    {
      int colL = w * 16 + (lane & 15);
      float bias = wk_b[s * 1280 + d0 + colL];
#pragma unroll
      for (int m = 0; m < 3; ++m)
#pragma unroll
        for (int r4 = 0; r4 < 4; ++r4) {
          float p = acc1[m][r4] + bias;
          p = fminf(fmaxf(p, -1.f), 1.f);
          int prow = m * 16 + (lane >> 4) * 4 + r4;
          int off  = prow * 128 + ((colL * 2) ^ ((prow & 7) << 4));
          *(u16*)(sm + PT_OFF + off) = f2bf(p);
        }
    }
    __syncthreads();

#pragma unroll
    for (int ks = 0; ks < 2; ++ks) {
      int erow = w * 16 + (lane & 15);
      int ekb  = (ks * 64 + (lane >> 4) * 16) ^ ((erow & 7) << 4);
      bf16x8 efrag = lds_frag(sm, ET_OFF + erow * 128 + ekb);
#pragma unroll
      for (int m = 0; m < 3; ++m) {
        int prow = m * 16 + (lane & 15);
        int pkb  = (ks * 64 + (lane >> 4) * 16) ^ ((prow & 7) << 4);
        bf16x8 pfrag = lds_frag(sm, PT_OFF + prow * 128 + pkb);
        acc2[m] = MFMA16(pfrag, efrag, acc2[m]);
      }
    }
  }

#pragma unroll
  for (int m = 0; m < 3; ++m)
#pragma unroll
    for (int r4 = 0; r4 < 4; ++r4) {
      int row = m * 16 + (lane >> 4) * 4 + r4;
      int q = w * 16 + (lane & 15);
      if (row < Ms && q < 49)
        dots[((size_t)(b * 5 + s) * 42 + row) * 49 + q] = acc2[m][r4];
    }
}

// ---------------------------------------------------------------------------
// Loss + accuracy -> directly into d_out[2] (pre-zeroed), scaled by 1/8960
// ---------------------------------------------------------------------------
__global__ __launch_bounds__(256) void loss_kernel(
    const float* __restrict__ dots, const int* __restrict__ neg_rows,
    const int* __restrict__ neg_cols, float* __restrict__ out)
{
  int gid = blockIdx.x * 256 + threadIdx.x;
  float lsum = 0.f, csum = 0.f;
  if (gid < 8960) {
    int b = gid / 140;
    int rem = gid % 140;
    int p = rem / 7, c = rem % 7;
    int s, r;
    if      (p < 6)  { s = 0; r = p; }
    else if (p < 11) { s = 1; r = p - 6; }
    else if (p < 15) { s = 2; r = p - 11; }
    else if (p < 18) { s = 3; r = p - 15; }
    else             { s = 4; r = p - 18; }

    const float* drow = &dots[((size_t)(b * 5 + s) * 42 + r * 7 + c) * 49];
    float d[17];
    d[0] = drow[r * 7 + c];
    const int nbase = (((b * 5 + s) * 6 + r) * 7 + c) * 16;
#pragma unroll
    for (int j = 0; j < 16; ++j) {
      int q = neg_rows[nbase + j] * 7 + neg_cols[nbase + j];
      d[1 + j] = drow[q];
    }
    float m = d[0];
#pragma unroll
    for (int j = 1; j < 17; ++j) m = fmaxf(m, d[j]);
    float se = 0.f;
#pragma unroll
    for (int j = 0; j < 17; ++j) se += expf(d[j] - m);
    lsum = -(d[0] - m - logf(se));
    csum = (d[0] >= m) ? 1.f : 0.f;
  }

#pragma unroll
  for (int off = 32; off > 0; off >>= 1) {
    lsum += __shfl_down(lsum, off);
    csum += __shfl_down(csum, off);
  }
  __shared__ float red[8];
  int wid = threadIdx.x >> 6;
  if ((threadIdx.x & 63) == 0) { red[wid * 2] = lsum; red[wid * 2 + 1] = csum; }
  __syncthreads();
  if (threadIdx.x == 0) {
    atomicAdd(&out[0], (red[0] + red[2] + red[4] + red[6]) * (1.f / 8960.f));
    atomicAdd(&out[1], (red[1] + red[3] + red[5] + red[7]) * (1.f / 8960.f));
  }
}

// ---------------------------------------------------------------------------
extern "C" void kernel_launch(void* const* d_in, const int* in_sizes, int n_in,
                              void* d_out, int out_size, void* d_ws, size_t ws_size,
                              hipStream_t stream)
{
  const float* enc    = (const float*)d_in[0];
  const float* hidden = (const float*)d_in[1];
  const float* w_ih   = (const float*)d_in[2];
  const float* w_hh   = (const float*)d_in[3];
  const float* b_ih   = (const float*)d_in[4];
  const float* b_hh   = (const float*)d_in[5];
  const float* wk_w   = (const float*)d_in[6];
  const float* wk_b   = (const float*)d_in[7];
  const int* neg_rows = (const int*)d_in[8];
  const int* neg_cols = (const int*)d_in[9];
  float* out = (float*)d_out;

  float* ws    = (float*)d_ws;
  float* gi    = ws;                                // [6*448][768] f32
  u16*   ctxb  = (u16*)(gi + 6 * 448 * 768);        // [6*448][256] bf16
  u16*   encb  = ctxb + 6 * 448 * 256;              // [64*49][1280] bf16
  u16*   wkwb  = encb + 64 * 49 * 1280;             // [5][1280][256] bf16
  u16*   wihb  = wkwb + 5 * 1280 * 256;             // [768][1280] bf16
  u16*   whhpk = wihb + 768 * 1280;                 // [48*8*64*8] bf16 packed
  float* dotsb = (float*)(whhpk + 768 * 256 + 768); // [64][5][42][49] f32

  hipMemsetAsync(out, 0, 2 * sizeof(float), stream);

  cvt3<<<6482, 256, 0, stream>>>(enc, wk_w, w_ih, encb, wkwb, wihb);
  pack_whh<<<96, 256, 0, stream>>>(w_hh, whhpk);

  gi_mfma<<<dim3(6, 21), 256, 0, stream>>>(encb, wihb, b_ih, gi);

  gru_fused<<<28, 512, 0, stream>>>(whhpk, b_hh, hidden, gi, ctxb);

  fused_pd<<<dim3(64, 5), 256, 0, stream>>>(ctxb, wkwb, wk_b, encb, dotsb);

  loss_kernel<<<35, 256, 0, stream>>>(dotsb, neg_rows, neg_cols, out);
}

// Round 7
// 130.104 us; speedup vs baseline: 6.5471x; 1.0202x over previous
//
#include <hip/hip_runtime.h>
#include <math.h>

// B=64, ROWS=7, COLS=7, D=1280, H=256, S=5, NEG=16, GRU_ROWS=6
// valid (s,r): r < 6-s -> 20 pairs; num_preds = 20*64*7 = 8960

typedef __bf16 bf16x8 __attribute__((ext_vector_type(8)));
typedef float  f32x4  __attribute__((ext_vector_type(4)));
typedef unsigned short u16;
typedef unsigned int u32;

__device__ inline u16 f2bf(float f) {           // RNE f32 -> bf16 bits
  unsigned int u = __float_as_uint(f);
  u += 0x7fff + ((u >> 16) & 1);
  return (u16)(u >> 16);
}

__device__ inline bf16x8 lds_frag(const char* sm, int off) {
  return __builtin_bit_cast(bf16x8, *(const uint4*)(sm + off));
}

// async global->LDS 16B per lane (wave-uniform LDS base, per-lane global src)
__device__ inline void gld_lds16(const void* g, void* l) {
  __builtin_amdgcn_global_load_lds(
      (const __attribute__((address_space(1))) u32*)g,
      (__attribute__((address_space(3))) u32*)l, 16, 0, 0);
}

#define MFMA16(a, b, c) __builtin_amdgcn_mfma_f32_16x16x32_bf16(a, b, c, 0, 0, 0)

// ---------------------------------------------------------------------------
// One-shot f32->bf16 for enc | wk_w | w_ih (three consecutive ranges)
// ---------------------------------------------------------------------------
__global__ __launch_bounds__(256) void cvt3(
    const float* __restrict__ enc, const float* __restrict__ wkw,
    const float* __restrict__ wih,
    u16* __restrict__ encb, u16* __restrict__ wkwb, u16* __restrict__ wihb)
{
  const int N1 = 64 * 49 * 1280;
  const int N2 = N1 + 5 * 1280 * 256;
  const int N3 = N2 + 768 * 1280;
  int i4 = (blockIdx.x * 256 + threadIdx.x) * 4;
  const float* src; u16* dst; int off;
  if (i4 < N1)      { src = enc; dst = encb; off = i4; }
  else if (i4 < N2) { src = wkw; dst = wkwb; off = i4 - N1; }
  else if (i4 < N3) { src = wih; dst = wihb; off = i4 - N2; }
  else return;
  float4 v = *(const float4*)&src[off];
  ushort4 o;
  o.x = f2bf(v.x); o.y = f2bf(v.y); o.z = f2bf(v.z); o.w = f2bf(v.w);
  *(ushort4*)&dst[off] = o;
}

// ---------------------------------------------------------------------------
// Pack w_hh [768][256] f32 -> per-lane MFMA B-fragment order (bf16),
// GATE-INTERLEAVED: fragment cb = w*6 + nf, nf = g*2 + half maps to
// weight col = g*256 + w*32 + half*16 + (lane&15), k = ks*32 + (lane>>4)*8.
// Byte layout: (cb*8 + ks)*1024 + lane*16.
// ---------------------------------------------------------------------------
__global__ __launch_bounds__(256) void pack_whh(
    const float* __restrict__ w_hh, u16* __restrict__ pk)
{
  int tid = blockIdx.x * 256 + threadIdx.x;  // 0..24575
  int lane = tid & 63;
  int rest = tid >> 6;                       // cb*8 + ks
  int cb = rest >> 3, ks = rest & 7;
  int w = cb / 6, nf = cb % 6;
  int g = nf >> 1, half = nf & 1;
  int col = g * 256 + w * 32 + half * 16 + (lane & 15);
  int k = ks * 32 + (lane >> 4) * 8;
  const float* src = &w_hh[(size_t)col * 256 + k];
  float4 v0 = *(const float4*)src;
  float4 v1 = *(const float4*)(src + 4);
  u16 o[8] = {f2bf(v0.x), f2bf(v0.y), f2bf(v0.z), f2bf(v0.w),
              f2bf(v1.x), f2bf(v1.y), f2bf(v1.z), f2bf(v1.w)};
  *(uint4*)&pk[(size_t)tid * 8] = *(uint4*)o;
}

// ---------------------------------------------------------------------------
// gi = enc @ w_ih^T + b_ih via bf16 MFMA. (unchanged)
// ---------------------------------------------------------------------------
__global__ __launch_bounds__(256) void gi_mfma(
    const u16* __restrict__ encb, const u16* __restrict__ wihb,
    const float* __restrict__ b_ih, float* __restrict__ gi)
{
  const int bx = blockIdx.x, by = blockIdx.y;
  const int t = threadIdx.x, lane = t & 63, w = t >> 6;
  const int wr = w >> 1, wc = w & 1;

  __shared__ char sm[32768];
  const int A_OFF = 0, B_OFF = 16384;

  f32x4 acc[4][4];
#pragma unroll
  for (int i = 0; i < 4; ++i)
#pragma unroll
    for (int j = 0; j < 4; ++j) acc[i][j] = (f32x4){0.f, 0.f, 0.f, 0.f};

  for (int k0 = 0; k0 < 1280; k0 += 64) {
    if (k0) __syncthreads();
#pragma unroll
    for (int j = 0; j < 4; ++j) {
      int u = j * 256 + t;
      int row = u >> 3, slot = u & 7;
      int m = by * 128 + row;
      int r = m / 448, n = m - r * 448;
      int b = n / 7, c = n - b * 7;
      uint4 v = *(const uint4*)&encb[(size_t)(b * 49 + r * 7 + c) * 1280 + k0 + slot * 8];
      *(uint4*)(sm + A_OFF + row * 128 + ((slot * 16) ^ ((row & 7) << 4))) = v;
    }
#pragma unroll
    for (int j = 0; j < 4; ++j) {
      int u = j * 256 + t;
      int row = u >> 3, slot = u & 7;
      uint4 v = *(const uint4*)&wihb[(size_t)(bx * 128 + row) * 1280 + k0 + slot * 8];
      *(uint4*)(sm + B_OFF + row * 128 + ((slot * 16) ^ ((row & 7) << 4))) = v;
    }
    __syncthreads();
#pragma unroll
    for (int ks = 0; ks < 2; ++ks) {
      bf16x8 a[4], b[4];
#pragma unroll
      for (int i = 0; i < 4; ++i) {
        int arow = wr * 64 + i * 16 + (lane & 15);
        int akb  = (ks * 64 + (lane >> 4) * 16) ^ ((arow & 7) << 4);
        a[i] = lds_frag(sm, A_OFF + arow * 128 + akb);
        int brow = wc * 64 + i * 16 + (lane & 15);
        int bkb  = (ks * 64 + (lane >> 4) * 16) ^ ((brow & 7) << 4);
        b[i] = lds_frag(sm, B_OFF + brow * 128 + bkb);
      }
#pragma unroll
      for (int i = 0; i < 4; ++i)
#pragma unroll
        for (int jn = 0; jn < 4; ++jn)
          acc[i][jn] = MFMA16(a[i], b[jn], acc[i][jn]);
    }
  }

#pragma unroll
  for (int i = 0; i < 4; ++i)
#pragma unroll
    for (int jn = 0; jn < 4; ++jn) {
      int gcol = bx * 128 + wc * 64 + jn * 16 + (lane & 15);
      float bias = b_ih[gcol];
#pragma unroll
      for (int r4 = 0; r4 < 4; ++r4) {
        int grow = by * 128 + wr * 64 + i * 16 + (lane >> 4) * 4 + r4;
        gi[(size_t)grow * 768 + gcol] = acc[i][jn][r4] + bias;
      }
    }
}

// ---------------------------------------------------------------------------
// GRU, one kernel, 28 blocks x 512 thr (8 waves), 16 seqs/block.
// NO resident weights (rounds 3/5/6: RA caps at 128 VGPR and spills them).
// Weights streamed all-6 per ks with an explicit 2-stage register pipeline
// (48 VGPR dest, static indexing); gi staged async into double-buffered LDS
// via global_load_lds (zero VGPR cost), one step ahead. Pointwise in regs.
// Live set ~115 VGPR -> fits the 128 budget with no spill.
// ---------------------------------------------------------------------------
__global__ __launch_bounds__(512) void gru_fused(
    const u16* __restrict__ whh_pk, const float* __restrict__ b_hh,
    const float* __restrict__ hidden, const float* __restrict__ gi,
    u16* __restrict__ ctxb)
{
  const int n0 = blockIdx.x * 16;
  const int t = threadIdx.x, lane = t & 63, w = t >> 6;

  // LDS: h dbuf 2x8KB | gi dbuf 2x48KB
  __shared__ char sm[16384 + 2 * 49152];
  const int GI0 = 16384;

  const int l15 = lane & 15;
  const int seq0 = (lane >> 4) * 4;
  const int hc0 = w * 32 + l15, hc1 = w * 32 + 16 + l15;

  const float br0 = b_hh[hc0],       br1 = b_hh[hc1];
  const float bz0 = b_hh[256 + hc0], bz1 = b_hh[256 + hc1];
  const float bn0 = b_hh[512 + hc0], bn1 = b_hh[512 + hc1];

  // stage gi[0] -> gi buffer 0 (async; drained by prologue barrier)
#pragma unroll
  for (int i = 0; i < 6; ++i) {
    int chunk = w * 6 + i;   // 1KB chunks of the 48KB slice
    gld_lds16(gi + (size_t)n0 * 768 + chunk * 256 + lane * 4,
              sm + GI0 + chunk * 1024);
  }

  // init h (f32 in regs, bf16 in LDS buffer 0)
  float hold[2][4];
  {
    float h0 = hidden[hc0], h1 = hidden[hc1];
#pragma unroll
    for (int r4 = 0; r4 < 4; ++r4) { hold[0][r4] = h0; hold[1][r4] = h1; }
    u16 hb0 = f2bf(h0), hb1 = f2bf(h1);
#pragma unroll
    for (int r4 = 0; r4 < 4; ++r4) {
      int seq = seq0 + r4;
      *(u16*)(sm + seq * 512 + ((hc0 * 2) ^ ((seq & 7) << 4))) = hb0;
      *(u16*)(sm + seq * 512 + ((hc1 * 2) ^ ((seq & 7) << 4))) = hb1;
    }
  }
  __syncthreads();

  for (int r = 0; r < 6; ++r) {
    const char* hb  = sm + (r & 1) * 8192;
    char* hbn       = sm + ((r + 1) & 1) * 8192;
    const char* gbr = sm + GI0 + (r & 1) * 49152;

    // prefetch gi[r+1] (buffer last read by pointwise r-1 -> free)
    if (r + 1 < 6) {
#pragma unroll
      for (int i = 0; i < 6; ++i) {
        int chunk = w * 6 + i;
        gld_lds16(gi + (size_t)((r + 1) * 448 + n0) * 768 + chunk * 256 + lane * 4,
                  sm + GI0 + ((r + 1) & 1) * 49152 + chunk * 1024);
      }
    }

    uintptr_t pa = (uintptr_t)whh_pk;
    asm volatile("" : "+v"(pa));        // defeat cross-step load hoisting
    const char* pkb = (const char*)pa + w * 49152 + lane * 16;

    f32x4 acc[6];
#pragma unroll
    for (int nf = 0; nf < 6; ++nf) acc[nf] = (f32x4){0.f, 0.f, 0.f, 0.f};

    // 2-stage weight pipeline over ks (all static indexing)
    bf16x8 bA[6], bB[6];
#pragma unroll
    for (int nf = 0; nf < 6; ++nf) bA[nf] = *(const bf16x8*)(pkb + nf * 8192);
#pragma unroll
    for (int kp = 0; kp < 4; ++kp) {
      const int ks0 = kp * 2, ks1 = kp * 2 + 1;
#pragma unroll
      for (int nf = 0; nf < 6; ++nf)
        bB[nf] = *(const bf16x8*)(pkb + nf * 8192 + ks1 * 1024);
      {
        bf16x8 a = lds_frag(hb, l15 * 512 +
                            ((ks0 * 64 + (lane >> 4) * 16) ^ ((l15 & 7) << 4)));
#pragma unroll
        for (int nf = 0; nf < 6; ++nf) acc[nf] = MFMA16(a, bA[nf], acc[nf]);
      }
      if (kp < 3) {
#pragma unroll
        for (int nf = 0; nf < 6; ++nf)
          bA[nf] = *(const bf16x8*)(pkb + nf * 8192 + (ks0 + 2) * 1024);
      }
      {
        bf16x8 a = lds_frag(hb, l15 * 512 +
                            ((ks1 * 64 + (lane >> 4) * 16) ^ ((l15 & 7) << 4)));
#pragma unroll
        for (int nf = 0; nf < 6; ++nf) acc[nf] = MFMA16(a, bB[nf], acc[nf]);
      }
    }

    __syncthreads();   // gi[r] staged (vmcnt drain) + hbn free of readers

    // pointwise in registers: acc[0+half]=r, acc[2+half]=z, acc[4+half]=n
#pragma unroll
    for (int r4 = 0; r4 < 4; ++r4) {
      int seq = seq0 + r4;
      float ir0 = *(const float*)(gbr + (size_t)(seq * 768 + hc0) * 4);
      float iz0 = *(const float*)(gbr + (size_t)(seq * 768 + 256 + hc0) * 4);
      float in0 = *(const float*)(gbr + (size_t)(seq * 768 + 512 + hc0) * 4);
      float ir1 = *(const float*)(gbr + (size_t)(seq * 768 + hc1) * 4);
      float iz1 = *(const float*)(gbr + (size_t)(seq * 768 + 256 + hc1) * 4);
      float in1 = *(const float*)(gbr + (size_t)(seq * 768 + 512 + hc1) * 4);
      {
        float rg = 1.f / (1.f + expf(-(ir0 + acc[0][r4] + br0)));
        float zg = 1.f / (1.f + expf(-(iz0 + acc[2][r4] + bz0)));
        float ng = tanhf(in0 + rg * (acc[4][r4] + bn0));
        float hnew = (1.f - zg) * ng + zg * hold[0][r4];
        hold[0][r4] = hnew;
        u16 hb16 = f2bf(hnew);
        *(u16*)(hbn + seq * 512 + ((hc0 * 2) ^ ((seq & 7) << 4))) = hb16;
        ctxb[(size_t)(r * 448 + n0 + seq) * 256 + hc0] = hb16;
      }
      {
        float rg = 1.f / (1.f + expf(-(ir1 + acc[1][r4] + br1)));
        float zg = 1.f / (1.f + expf(-(iz1 + acc[3][r4] + bz1)));
        float ng = tanhf(in1 + rg * (acc[5][r4] + bn1));
        float hnew = (1.f - zg) * ng + zg * hold[1][r4];
        hold[1][r4] = hnew;
        u16 hb16 = f2bf(hnew);
        *(u16*)(hbn + seq * 512 + ((hc1 * 2) ^ ((seq & 7) << 4))) = hb16;
        ctxb[(size_t)(r * 448 + n0 + seq) * 256 + hc1] = hb16;
      }
    }
    __syncthreads();   // hbn complete before next step's MFMA
  }
}

// ---------------------------------------------------------------------------
// Fused preds+dots, bf16 MFMA. Block (b, s). (unchanged)
// ---------------------------------------------------------------------------
__global__ __launch_bounds__(256) void fused_pd(
    const u16* __restrict__ ctxb, const u16* __restrict__ wkwb,
    const float* __restrict__ wk_b, const u16* __restrict__ encb,
    float* __restrict__ dots)
{
  const int b = blockIdx.x;
  const int s = blockIdx.y;
  const int Ms = (6 - s) * 7;
  const int t = threadIdx.x;
  const int lane = t & 63, w = t >> 6;

  __shared__ uint4 smem4[71680 / 16];
  char* sm = (char*)smem4;
  const int CTX_OFF = 0, WT_OFF = 24576, ET_OFF = 57344, PT_OFF = 65536;

#pragma unroll
  for (int j = 0; j < 6; ++j) {
    int u = j * 256 + t;
    int row = u >> 5, slot = u & 31;
    int rr = row < Ms ? row : 0;
    int r = rr / 7, c = rr - r * 7;
    uint4 v = *(const uint4*)&ctxb[((size_t)(r * 448 + b * 7 + c)) * 256 + slot * 8];
    int off = row * 512 + ((slot * 16) ^ ((row & 7) << 4));
    *(uint4*)(sm + CTX_OFF + off) = v;
  }
  __syncthreads();

  bf16x8 a1[3][8];
#pragma unroll
  for (int m = 0; m < 3; ++m)
#pragma unroll
    for (int ks = 0; ks < 8; ++ks) {
      int row = m * 16 + (lane & 15);
      int kb  = (ks * 64 + (lane >> 4) * 16) ^ ((row & 7) << 4);
      a1[m][ks] = lds_frag(sm, CTX_OFF + row * 512 + kb);
    }

  f32x4 acc2[3];
#pragma unroll
  for (int m = 0; m < 3; ++m) acc2[m] = (f32x4){0.f, 0.f, 0.f, 0.f};

  for (int ch = 0; ch < 20; ++ch) {
    const int d0 = ch * 64;
    if (ch) __syncthreads();

#pragma unroll
    for (int j = 0; j < 8; ++j) {
      int u = j * 256 + t;
      int row = u >> 5, slot = u & 31;
      uint4 v = *(const uint4*)&wkwb[((size_t)s * 1280 + d0 + row) * 256 + slot * 8];
      int off = row * 512 + ((slot * 16) ^ ((row & 7) << 4));
      *(uint4*)(sm + WT_OFF + off) = v;
    }
#pragma unroll
    for (int j = 0; j < 2; ++j) {
      int u = j * 256 + t;
      int row = u >> 3, slot = u & 7;
      int q = row < 49 ? row : 0;
      uint4 v = *(const uint4*)&encb[((size_t)(b * 49 + q)) * 1280 + d0 + slot * 8];
      int off = row * 128 + ((slot * 16) ^ ((row & 7) << 4));
      *(uint4*)(sm + ET_OFF + off) = v;
    }
    __syncthreads();

    f32x4 acc1[3];
#pragma unroll
    for (int m = 0; m < 3; ++m) acc1[m] = (f32x4){0.f, 0.f, 0.f, 0.f};
#pragma unroll
    for (int ks = 0; ks < 8; ++ks) {
      int row = w * 16 + (lane & 15);
      int kb  = (ks * 64 + (lane >> 4) * 16) ^ ((row & 7) << 4);
      bf16x8 bfrag = lds_frag(sm, WT_OFF + row * 512 + kb);
      acc1[0] = MFMA16(a1[0][ks], bfrag, acc1[0]);
      acc1[1] = MFMA16(a1[1][ks], bfrag, acc1[1]);
      acc1[2] = MFMA16(a1[2][ks], bfrag, acc1[2]);
    }
    {
      int colL = w * 16 + (lane & 15);
      float bias = wk_b[s * 1280 + d0 + colL];
#pragma unroll
      for (int m = 0; m < 3; ++m)
#pragma unroll
        for (int r4 = 0; r4 < 4; ++r4) {
          float p = acc1[m][r4] + bias;
          p = fminf(fmaxf(p, -1.f), 1.f);
          int prow = m * 16 + (lane >> 4) * 4 + r4;
          int off  = prow * 128 + ((colL * 2) ^ ((prow & 7) << 4));
          *(u16*)(sm + PT_OFF + off) = f2bf(p);
        }
    }
    __syncthreads();

#pragma unroll
    for (int ks = 0; ks < 2; ++ks) {
      int erow = w * 16 + (lane & 15);
      int ekb  = (ks * 64 + (lane >> 4) * 16) ^ ((erow & 7) << 4);
      bf16x8 efrag = lds_frag(sm, ET_OFF + erow * 128 + ekb);
#pragma unroll
      for (int m = 0; m < 3; ++m) {
        int prow = m * 16 + (lane & 15);
        int pkb  = (ks * 64 + (lane >> 4) * 16) ^ ((prow & 7) << 4);
        bf16x8 pfrag = lds_frag(sm, PT_OFF + prow * 128 + pkb);
        acc2[m] = MFMA16(pfrag, efrag, acc2[m]);
      }
    }
  }

#pragma unroll
  for (int m = 0; m < 3; ++m)
#pragma unroll
    for (int r4 = 0; r4 < 4; ++r4) {
      int row = m * 16 + (lane >> 4) * 4 + r4;
      int q = w * 16 + (lane & 15);
      if (row < Ms && q < 49)
        dots[((size_t)(b * 5 + s) * 42 + row) * 49 + q] = acc2[m][r4];
    }
}

// ---------------------------------------------------------------------------
// Loss + accuracy -> directly into d_out[2] (pre-zeroed), scaled by 1/8960
// ---------------------------------------------------------------------------
__global__ __launch_bounds__(256) void loss_kernel(
    const float* __restrict__ dots, const int* __restrict__ neg_rows,
    const int* __restrict__ neg_cols, float* __restrict__ out)
{
  int gid = blockIdx.x * 256 + threadIdx.x;
  float lsum = 0.f, csum = 0.f;
  if (gid < 8960) {
    int b = gid / 140;
    int rem = gid % 140;
    int p = rem / 7, c = rem % 7;
    int s, r;
    if      (p < 6)  { s = 0; r = p; }
    else if (p < 11) { s = 1; r = p - 6; }
    else if (p < 15) { s = 2; r = p - 11; }
    else if (p < 18) { s = 3; r = p - 15; }
    else             { s = 4; r = p - 18; }

    const float* drow = &dots[((size_t)(b * 5 + s) * 42 + r * 7 + c) * 49];
    float d[17];
    d[0] = drow[r * 7 + c];
    const int nbase = (((b * 5 + s) * 6 + r) * 7 + c) * 16;
#pragma unroll
    for (int j = 0; j < 16; ++j) {
      int q = neg_rows[nbase + j] * 7 + neg_cols[nbase + j];
      d[1 + j] = drow[q];
    }
    float m = d[0];
#pragma unroll
    for (int j = 1; j < 17; ++j) m = fmaxf(m, d[j]);
    float se = 0.f;
#pragma unroll
    for (int j = 0; j < 17; ++j) se += expf(d[j] - m);
    lsum = -(d[0] - m - logf(se));
    csum = (d[0] >= m) ? 1.f : 0.f;
  }

#pragma unroll
  for (int off = 32; off > 0; off >>= 1) {
    lsum += __shfl_down(lsum, off);
    csum += __shfl_down(csum, off);
  }
  __shared__ float red[8];
  int wid = threadIdx.x >> 6;
  if ((threadIdx.x & 63) == 0) { red[wid * 2] = lsum; red[wid * 2 + 1] = csum; }
  __syncthreads();
  if (threadIdx.x == 0) {
    atomicAdd(&out[0], (red[0] + red[2] + red[4] + red[6]) * (1.f / 8960.f));
    atomicAdd(&out[1], (red[1] + red[3] + red[5] + red[7]) * (1.f / 8960.f));
  }
}

// ---------------------------------------------------------------------------
extern "C" void kernel_launch(void* const* d_in, const int* in_sizes, int n_in,
                              void* d_out, int out_size, void* d_ws, size_t ws_size,
                              hipStream_t stream)
{
  const float* enc    = (const float*)d_in[0];
  const float* hidden = (const float*)d_in[1];
  const float* w_ih   = (const float*)d_in[2];
  const float* w_hh   = (const float*)d_in[3];
  const float* b_ih   = (const float*)d_in[4];
  const float* b_hh   = (const float*)d_in[5];
  const float* wk_w   = (const float*)d_in[6];
  const float* wk_b   = (const float*)d_in[7];
  const int* neg_rows = (const int*)d_in[8];
  const int* neg_cols = (const int*)d_in[9];
  float* out = (float*)d_out;

  float* ws    = (float*)d_ws;
  float* gi    = ws;                                // [6*448][768] f32
  u16*   ctxb  = (u16*)(gi + 6 * 448 * 768);        // [6*448][256] bf16
  u16*   encb  = ctxb + 6 * 448 * 256;              // [64*49][1280] bf16
  u16*   wkwb  = encb + 64 * 49 * 1280;             // [5][1280][256] bf16
  u16*   wihb  = wkwb + 5 * 1280 * 256;             // [768][1280] bf16
  u16*   whhpk = wihb + 768 * 1280;                 // [48*8*64*8] bf16 packed
  float* dotsb = (float*)(whhpk + 768 * 256 + 768); // [64][5][42][49] f32

  hipMemsetAsync(out, 0, 2 * sizeof(float), stream);

  cvt3<<<6482, 256, 0, stream>>>(enc, wk_w, w_ih, encb, wkwb, wihb);
  pack_whh<<<96, 256, 0, stream>>>(w_hh, whhpk);

  gi_mfma<<<dim3(6, 21), 256, 0, stream>>>(encb, wihb, b_ih, gi);

  gru_fused<<<28, 512, 0, stream>>>(whhpk, b_hh, hidden, gi, ctxb);

  fused_pd<<<dim3(64, 5), 256, 0, stream>>>(ctxb, wkwb, wk_b, encb, dotsb);

  loss_kernel<<<35, 256, 0, stream>>>(dotsb, neg_rows, neg_cols, out);
}